// Round 1
// baseline (767.032 us; speedup 1.0000x reference)
//
#include <hip/hip_runtime.h>
#include <math.h>

#define DD 256
static constexpr int N_MET  = 2534;
static constexpr int N_RXN  = 4881;
static constexpr int N_GENE = 6607;
static constexpr int NE     = 262144;
static constexpr int NP     = 131072;

// ---------- block reductions (blockDim.x == 256, wave64) ----------
__device__ __forceinline__ float blockReduceSum256(float v) {
  __shared__ float s[4];
  #pragma unroll
  for (int o = 32; o > 0; o >>= 1) v += __shfl_down(v, o, 64);
  __syncthreads();
  if ((threadIdx.x & 63) == 0) s[threadIdx.x >> 6] = v;
  __syncthreads();
  return s[0] + s[1] + s[2] + s[3];
}

__device__ __forceinline__ float blockReduceMax256(float v) {
  __shared__ float s[4];
  #pragma unroll
  for (int o = 32; o > 0; o >>= 1) v = fmaxf(v, __shfl_down(v, o, 64));
  __syncthreads();
  if ((threadIdx.x & 63) == 0) s[threadIdx.x >> 6] = v;
  __syncthreads();
  return fmaxf(fmaxf(s[0], s[1]), fmaxf(s[2], s[3]));
}

// ---------- CSR building ----------
__global__ void hist2_k(const int* __restrict__ a, const int* __restrict__ b, int n,
                        int* cntA, int* cntB) {
  int i = blockIdx.x * blockDim.x + threadIdx.x;
  if (i < n) { atomicAdd(&cntA[a[i]], 1); atomicAdd(&cntB[b[i]], 1); }
}

__global__ void fill2_k(const int* __restrict__ a, const int* __restrict__ b, int n,
                        int* curA, int* __restrict__ idxA,
                        int* curB, int* __restrict__ idxB) {
  int i = blockIdx.x * blockDim.x + threadIdx.x;
  if (i < n) {
    int pa = atomicAdd(&curA[a[i]], 1); idxA[pa] = i;
    int pb = atomicAdd(&curB[b[i]], 1); idxB[pb] = i;
  }
}

// exclusive scan of 4 arrays (n <= 8192 each), one block per array
__global__ void scan4_k(const int* c0, int n0, int* o0, int* u0,
                        const int* c1, int n1, int* o1, int* u1,
                        const int* c2, int n2, int* o2, int* u2,
                        const int* c3, int n3, int* o3, int* u3) {
  const int* cnt; int n; int* offs; int* cur;
  if      (blockIdx.x == 0) { cnt = c0; n = n0; offs = o0; cur = u0; }
  else if (blockIdx.x == 1) { cnt = c1; n = n1; offs = o1; cur = u1; }
  else if (blockIdx.x == 2) { cnt = c2; n = n2; offs = o2; cur = u2; }
  else                      { cnt = c3; n = n3; offs = o3; cur = u3; }
  __shared__ int part[1024];
  int tid = threadIdx.x;
  int base = tid * 8;
  int v[8]; int s = 0;
  #pragma unroll
  for (int j = 0; j < 8; ++j) { int x = (base + j < n) ? cnt[base + j] : 0; v[j] = x; s += x; }
  part[tid] = s;
  __syncthreads();
  for (int o = 1; o < 1024; o <<= 1) {
    int t = (tid >= o) ? part[tid - o] : 0;
    __syncthreads();
    part[tid] += t;
    __syncthreads();
  }
  int ex = part[tid] - s;
  #pragma unroll
  for (int j = 0; j < 8; ++j) {
    if (base + j < n) { offs[base + j] = ex; cur[base + j] = ex; ex += v[j]; }
  }
  if (tid == 1023) offs[n] = part[1023];
}

// ---------- small dense ops ----------
__global__ void renorm_k(const float* __restrict__ emb, float* __restrict__ met) {
  int r = blockIdx.x, tid = threadIdx.x;
  float v = emb[(size_t)r * DD + tid];
  float ss = blockReduceSum256(v * v);
  float sc = fminf(1.f, 1.f / (sqrtf(ss) + 1e-12f));
  met[(size_t)r * DD + tid] = v * sc;
}

// out[r] = dot(A[r,:], v), one wave per row
__global__ void rowdot_k(const float* __restrict__ A, const float* __restrict__ v,
                         float* __restrict__ out, int M) {
  int w = threadIdx.x >> 6, lane = threadIdx.x & 63;
  int r = blockIdx.x * 4 + w;
  if (r >= M) return;
  const float* a = A + (size_t)r * DD;
  float acc = a[lane] * v[lane] + a[lane + 64] * v[lane + 64]
            + a[lane + 128] * v[lane + 128] + a[lane + 192] * v[lane + 192];
  #pragma unroll
  for (int o = 32; o > 0; o >>= 1) acc += __shfl_down(acc, o, 64);
  if (lane == 0) out[r] = acc;
}

// Y = X @ W, K = N = 256. 16 rows per block, 256 threads (one output column each).
__global__ __launch_bounds__(256) void gemm256_k(const float* __restrict__ X,
                                                 const float* __restrict__ W,
                                                 float* __restrict__ Y, int M) {
  __shared__ float Xs[256][20];  // k-major, padded; row base = k*80B (16B aligned)
  int tid = threadIdx.x;
  int r0 = blockIdx.x * 16;
  #pragma unroll
  for (int i = 0; i < 16; ++i) {
    int r = r0 + i;
    Xs[tid][i] = (r < M) ? X[(size_t)r * DD + tid] : 0.f;
  }
  __syncthreads();
  float acc[16];
  #pragma unroll
  for (int i = 0; i < 16; ++i) acc[i] = 0.f;
  const float* wp = W + tid;
  #pragma unroll 4
  for (int k = 0; k < 256; ++k) {
    float wv = wp[(size_t)k * DD];
    const float4* xr = reinterpret_cast<const float4*>(&Xs[k][0]);
    float4 a0 = xr[0], a1 = xr[1], a2 = xr[2], a3 = xr[3];
    acc[0]  += a0.x * wv; acc[1]  += a0.y * wv; acc[2]  += a0.z * wv; acc[3]  += a0.w * wv;
    acc[4]  += a1.x * wv; acc[5]  += a1.y * wv; acc[6]  += a1.z * wv; acc[7]  += a1.w * wv;
    acc[8]  += a2.x * wv; acc[9]  += a2.y * wv; acc[10] += a2.z * wv; acc[11] += a2.w * wv;
    acc[12] += a3.x * wv; acc[13] += a3.y * wv; acc[14] += a3.z * wv; acc[15] += a3.w * wv;
  }
  #pragma unroll
  for (int i = 0; i < 16; ++i) {
    int r = r0 + i;
    if (r < M) Y[(size_t)r * DD + tid] = acc[i];
  }
}

// ---------- segment ops ----------
// dst[r,:] = mean over CSR row of src[map[idx[j]], :]
__global__ void seg_mean_k(const int* __restrict__ offs, const int* __restrict__ idx,
                           const int* __restrict__ map, const float* __restrict__ src,
                           float* __restrict__ dst) {
  int r = blockIdx.x, tid = threadIdx.x;
  int beg = offs[r], end = offs[r + 1];
  float acc = 0.f;
  for (int j = beg; j < end; ++j) {
    int g = map[idx[j]];
    acc += src[(size_t)g * DD + tid];
  }
  int c = end - beg;
  dst[(size_t)r * DD + tid] = acc / (float)(c > 1 ? c : 1);
}

// per-reaction: softmax over incidences + weighted node->edge aggregation
__global__ void me_k(const int* __restrict__ offs, const int* __restrict__ idx,
                     const int* __restrict__ he_node, const float* __restrict__ stoich,
                     const float* __restrict__ sn, const float* __restrict__ se,
                     const float* __restrict__ xp, float* __restrict__ me,
                     float* __restrict__ wbuf) {
  int r = blockIdx.x, tid = threadIdx.x;
  int beg = offs[r], end = offs[r + 1];
  float ser = se[r];
  // pass 1: segment max of leaky_relu(sn[node] + se[r])
  float lmax = -1e30f;
  for (int j = beg + tid; j < end; j += 256) {
    int e = idx[j];
    float l = sn[he_node[e]] + ser;
    l = (l >= 0.f) ? l : 0.2f * l;
    lmax = fmaxf(lmax, l);
  }
  float m = blockReduceMax256(lmax);
  // pass 2: sum of exp
  float ls = 0.f;
  for (int j = beg + tid; j < end; j += 256) {
    int e = idx[j];
    float l = sn[he_node[e]] + ser;
    l = (l >= 0.f) ? l : 0.2f * l;
    ls += expf(l - m);
  }
  float S = blockReduceSum256(ls) + 1e-16f;
  // pass 3a: store w = stoich * alpha (parallel over incidences)
  for (int j = beg + tid; j < end; j += 256) {
    int e = idx[j];
    float l = sn[he_node[e]] + ser;
    l = (l >= 0.f) ? l : 0.2f * l;
    wbuf[e] = stoich[e] * expf(l - m) / S;
  }
  // pass 3b: accumulate w * xp[node] (serial over incidences, parallel over features)
  float acc = 0.f;
  for (int j = beg; j < end; ++j) {
    int e = idx[j];
    int n = he_node[e];
    float l = sn[n] + ser;
    l = (l >= 0.f) ? l : 0.2f * l;
    float wv = stoich[e] * expf(l - m) / S;
    acc += wv * xp[(size_t)n * DD + tid];
  }
  int c = end - beg;
  me[(size_t)r * DD + tid] = acc / (float)(c > 1 ? c : 1);
}

// per-metabolite: edge->node aggregation + bias + tanh (+ skip + layernorm for layer 1)
template <bool LN>
__global__ void out_k(const int* __restrict__ offs, const int* __restrict__ idx,
                      const int* __restrict__ he_edge, const float* __restrict__ wbuf,
                      const float* __restrict__ me, const float* __restrict__ bias,
                      const float* __restrict__ ln_g, const float* __restrict__ ln_b,
                      float* __restrict__ cur) {
  int n = blockIdx.x, tid = threadIdx.x;
  int beg = offs[n], end = offs[n + 1];
  float acc = 0.f;
  for (int j = beg; j < end; ++j) {
    int e = idx[j];
    int r = he_edge[e];
    acc += wbuf[e] * me[(size_t)r * DD + tid];
  }
  int c = end - beg;
  float o = acc / (float)(c > 1 ? c : 1) + bias[tid];
  float t = tanhf(o);
  if (!LN) {
    cur[(size_t)n * DD + tid] = t;
    return;
  }
  float z = t + cur[(size_t)n * DD + tid];
  float mu = blockReduceSum256(z) * (1.f / 256.f);
  float zc = z - mu;
  float var = blockReduceSum256(zc * zc) * (1.f / 256.f);
  cur[(size_t)n * DD + tid] = zc * (1.f / sqrtf(var + 1e-5f)) * ln_g[tid] + ln_b[tid];
}

// ---------- launcher ----------
extern "C" void kernel_launch(void* const* d_in, const int* in_sizes, int n_in,
                              void* d_out, int out_size, void* d_ws, size_t ws_size,
                              hipStream_t stream) {
  const int*   he_node = (const int*)d_in[0];
  const int*   he_edge = (const int*)d_in[1];
  const float* stoich  = (const float*)d_in[2];
  const float* gene_x  = (const float*)d_in[3];
  const int*   rtg_rxn = (const int*)d_in[4];
  const int*   rtg_gene= (const int*)d_in[5];
  const float* emb     = (const float*)d_in[6];
  const float* W0      = (const float*)d_in[7];
  const float* We0     = (const float*)d_in[8];
  const float* att0    = (const float*)d_in[9];
  const float* b0      = (const float*)d_in[10];
  const float* W1      = (const float*)d_in[11];
  const float* We1     = (const float*)d_in[12];
  const float* att1    = (const float*)d_in[13];
  const float* b1      = (const float*)d_in[14];
  const float* ln_g    = (const float*)d_in[15];
  const float* ln_b    = (const float*)d_in[16];
  float* out = (float*)d_out;

  char* base = (char*)d_ws;
  size_t off = 0;
  auto carve = [&](size_t bytes) -> char* {
    char* p = base + off;
    off += (bytes + 255) & ~(size_t)255;
    return p;
  };
  float* met     = (float*)carve((size_t)N_MET  * DD * 4);
  float* rxn_emb = (float*)carve((size_t)N_RXN  * DD * 4);
  float* xp      = (float*)carve((size_t)N_MET  * DD * 4);
  float* me      = (float*)carve((size_t)N_RXN  * DD * 4);
  float* cur     = (float*)carve((size_t)N_MET  * DD * 4);
  float* rxnf    = (float*)carve((size_t)N_RXN  * DD * 4);
  float* sn      = (float*)carve((size_t)N_MET * 4);
  float* se      = (float*)carve((size_t)N_RXN * 4);
  float* ve0     = (float*)carve(DD * 4);
  float* ve1     = (float*)carve(DD * 4);
  float* wbuf    = (float*)carve((size_t)NE * 4);
  int* cnts = (int*)carve((size_t)(N_RXN + N_MET + N_RXN + N_GENE) * 4);
  int* cntE = cnts;
  int* cntN = cntE + N_RXN;
  int* cntR = cntN + N_MET;
  int* cntG = cntR + N_RXN;
  int* offsE = (int*)carve((N_RXN + 1) * 4);
  int* curE  = (int*)carve(N_RXN * 4);
  int* idxE  = (int*)carve((size_t)NE * 4);
  int* offsN = (int*)carve((N_MET + 1) * 4);
  int* curN  = (int*)carve(N_MET * 4);
  int* idxN  = (int*)carve((size_t)NE * 4);
  int* offsR = (int*)carve((N_RXN + 1) * 4);
  int* curR  = (int*)carve(N_RXN * 4);
  int* idxR  = (int*)carve((size_t)NP * 4);
  int* offsG = (int*)carve((N_GENE + 1) * 4);
  int* curG  = (int*)carve(N_GENE * 4);
  int* idxG  = (int*)carve((size_t)NP * 4);

  // CSR build
  hipMemsetAsync(cnts, 0, (size_t)(N_RXN + N_MET + N_RXN + N_GENE) * 4, stream);
  hist2_k<<<(NE + 255) / 256, 256, 0, stream>>>(he_edge, he_node, NE, cntE, cntN);
  hist2_k<<<(NP + 255) / 256, 256, 0, stream>>>(rtg_rxn, rtg_gene, NP, cntR, cntG);
  scan4_k<<<4, 1024, 0, stream>>>(cntE, N_RXN, offsE, curE,
                                  cntN, N_MET, offsN, curN,
                                  cntR, N_RXN, offsR, curR,
                                  cntG, N_GENE, offsG, curG);
  fill2_k<<<(NE + 255) / 256, 256, 0, stream>>>(he_edge, he_node, NE, curE, idxE, curN, idxN);
  fill2_k<<<(NP + 255) / 256, 256, 0, stream>>>(rtg_rxn, rtg_gene, NP, curR, idxR, curG, idxG);

  // preprocessing
  renorm_k<<<N_MET, 256, 0, stream>>>(emb, met);
  seg_mean_k<<<N_RXN, 256, 0, stream>>>(offsR, idxR, rtg_gene, gene_x, rxn_emb);
  rowdot_k<<<(256 + 3) / 4, 256, 0, stream>>>(We0, att0 + DD, ve0, 256);
  rowdot_k<<<(256 + 3) / 4, 256, 0, stream>>>(We1, att1 + DD, ve1, 256);

  // layer 0
  gemm256_k<<<(N_MET + 15) / 16, 256, 0, stream>>>(met, W0, xp, N_MET);
  rowdot_k<<<(N_MET + 3) / 4, 256, 0, stream>>>(xp, att0, sn, N_MET);
  rowdot_k<<<(N_RXN + 3) / 4, 256, 0, stream>>>(rxn_emb, ve0, se, N_RXN);
  me_k<<<N_RXN, 256, 0, stream>>>(offsE, idxE, he_node, stoich, sn, se, xp, me, wbuf);
  out_k<false><<<N_MET, 256, 0, stream>>>(offsN, idxN, he_edge, wbuf, me, b0,
                                          nullptr, nullptr, cur);

  // layer 1 (skip + layernorm fused into out kernel)
  gemm256_k<<<(N_MET + 15) / 16, 256, 0, stream>>>(cur, W1, xp, N_MET);
  rowdot_k<<<(N_MET + 3) / 4, 256, 0, stream>>>(xp, att1, sn, N_MET);
  rowdot_k<<<(N_RXN + 3) / 4, 256, 0, stream>>>(rxn_emb, ve1, se, N_RXN);
  me_k<<<N_RXN, 256, 0, stream>>>(offsE, idxE, he_node, stoich, sn, se, xp, me, wbuf);
  out_k<true><<<N_MET, 256, 0, stream>>>(offsN, idxN, he_edge, wbuf, me, b1,
                                         ln_g, ln_b, cur);

  // final readout
  seg_mean_k<<<N_RXN, 256, 0, stream>>>(offsE, idxE, he_node, cur, rxnf);
  seg_mean_k<<<N_GENE, 256, 0, stream>>>(offsG, idxG, rtg_rxn, rxnf, out);
}

// Round 2
// 314.932 us; speedup vs baseline: 2.4355x; 2.4355x over previous
//
#include <hip/hip_runtime.h>
#include <math.h>

#define DD 256
static constexpr int N_MET  = 2534;
static constexpr int N_RXN  = 4881;
static constexpr int N_GENE = 6607;
static constexpr int NE     = 262144;
static constexpr int NP     = 131072;

// ---------- wave reductions (64 lanes) ----------
__device__ __forceinline__ float waveSum(float v) {
  #pragma unroll
  for (int o = 32; o > 0; o >>= 1) v += __shfl_xor(v, o, 64);
  return v;
}
__device__ __forceinline__ float waveMax(float v) {
  #pragma unroll
  for (int o = 32; o > 0; o >>= 1) v = fmaxf(v, __shfl_xor(v, o, 64));
  return v;
}

// ---------- CSR building ----------
__global__ void hist2_k(const int* __restrict__ a, const int* __restrict__ b, int n,
                        int* cntA, int* cntB) {
  int i = blockIdx.x * blockDim.x + threadIdx.x;
  if (i < n) { atomicAdd(&cntA[a[i]], 1); atomicAdd(&cntB[b[i]], 1); }
}

// fill CSR payloads directly (no idx indirection later)
__global__ void fill_he_k(const int* __restrict__ he_node, const int* __restrict__ he_edge,
                          const float* __restrict__ stoich,
                          int* curE, int* __restrict__ nodeE, float* __restrict__ stoE,
                          int* curN, int* __restrict__ edgeN, float* __restrict__ stoN) {
  int i = blockIdx.x * blockDim.x + threadIdx.x;
  if (i < NE) {
    int n = he_node[i], e = he_edge[i];
    float st = stoich[i];
    int pa = atomicAdd(&curE[e], 1); nodeE[pa] = n; stoE[pa] = st;
    int pb = atomicAdd(&curN[n], 1); edgeN[pb] = e; stoN[pb] = st;
  }
}

__global__ void fill_rtg_k(const int* __restrict__ rtg_rxn, const int* __restrict__ rtg_gene,
                           int* curR, int* __restrict__ geneR,
                           int* curG, int* __restrict__ rxnG) {
  int i = blockIdx.x * blockDim.x + threadIdx.x;
  if (i < NP) {
    int r = rtg_rxn[i], g = rtg_gene[i];
    int pa = atomicAdd(&curR[r], 1); geneR[pa] = g;
    int pb = atomicAdd(&curG[g], 1); rxnG[pb] = r;
  }
}

// exclusive scan of 4 arrays (n <= 8192 each), one block per array
__global__ void scan4_k(const int* c0, int n0, int* o0, int* u0,
                        const int* c1, int n1, int* o1, int* u1,
                        const int* c2, int n2, int* o2, int* u2,
                        const int* c3, int n3, int* o3, int* u3) {
  const int* cnt; int n; int* offs; int* cur;
  if      (blockIdx.x == 0) { cnt = c0; n = n0; offs = o0; cur = u0; }
  else if (blockIdx.x == 1) { cnt = c1; n = n1; offs = o1; cur = u1; }
  else if (blockIdx.x == 2) { cnt = c2; n = n2; offs = o2; cur = u2; }
  else                      { cnt = c3; n = n3; offs = o3; cur = u3; }
  __shared__ int part[1024];
  int tid = threadIdx.x;
  int base = tid * 8;
  int v[8]; int s = 0;
  #pragma unroll
  for (int j = 0; j < 8; ++j) { int x = (base + j < n) ? cnt[base + j] : 0; v[j] = x; s += x; }
  part[tid] = s;
  __syncthreads();
  for (int o = 1; o < 1024; o <<= 1) {
    int t = (tid >= o) ? part[tid - o] : 0;
    __syncthreads();
    part[tid] += t;
    __syncthreads();
  }
  int ex = part[tid] - s;
  #pragma unroll
  for (int j = 0; j < 8; ++j) {
    if (base + j < n) { offs[base + j] = ex; cur[base + j] = ex; ex += v[j]; }
  }
  if (tid == 1023) offs[n] = part[1023];
}

// ---------- small dense ops ----------
// wave per row: clamp row norm to <= 1
__global__ __launch_bounds__(256) void renorm_k(const float* __restrict__ emb,
                                                float* __restrict__ met) {
  int wid = (blockIdx.x * 256 + threadIdx.x) >> 6;
  int lane = threadIdx.x & 63;
  if (wid >= N_MET) return;
  float4 v = ((const float4*)emb)[(size_t)wid * 64 + lane];
  float ss = waveSum(v.x * v.x + v.y * v.y + v.z * v.z + v.w * v.w);
  float sc = fminf(1.f, 1.f / (sqrtf(ss) + 1e-12f));
  float4 o; o.x = v.x * sc; o.y = v.y * sc; o.z = v.z * sc; o.w = v.w * sc;
  ((float4*)met)[(size_t)wid * 64 + lane] = o;
}

// out[r] = dot(A[r,:], v), one wave per row
__global__ void rowdot_k(const float* __restrict__ A, const float* __restrict__ v,
                         float* __restrict__ out, int M) {
  int w = threadIdx.x >> 6, lane = threadIdx.x & 63;
  int r = blockIdx.x * 4 + w;
  if (r >= M) return;
  const float* a = A + (size_t)r * DD;
  float acc = a[lane] * v[lane] + a[lane + 64] * v[lane + 64]
            + a[lane + 128] * v[lane + 128] + a[lane + 192] * v[lane + 192];
  #pragma unroll
  for (int o = 32; o > 0; o >>= 1) acc += __shfl_down(acc, o, 64);
  if (lane == 0) out[r] = acc;
}

// Y = X @ W, K = N = 256. 16 rows per block, 256 threads (one output column each).
__global__ __launch_bounds__(256) void gemm256_k(const float* __restrict__ X,
                                                 const float* __restrict__ W,
                                                 float* __restrict__ Y, int M) {
  __shared__ float Xs[256][20];
  int tid = threadIdx.x;
  int r0 = blockIdx.x * 16;
  #pragma unroll
  for (int i = 0; i < 16; ++i) {
    int r = r0 + i;
    Xs[tid][i] = (r < M) ? X[(size_t)r * DD + tid] : 0.f;
  }
  __syncthreads();
  float acc[16];
  #pragma unroll
  for (int i = 0; i < 16; ++i) acc[i] = 0.f;
  const float* wp = W + tid;
  #pragma unroll 8
  for (int k = 0; k < 256; ++k) {
    float wv = wp[(size_t)k * DD];
    const float4* xr = reinterpret_cast<const float4*>(&Xs[k][0]);
    float4 a0 = xr[0], a1 = xr[1], a2 = xr[2], a3 = xr[3];
    acc[0]  += a0.x * wv; acc[1]  += a0.y * wv; acc[2]  += a0.z * wv; acc[3]  += a0.w * wv;
    acc[4]  += a1.x * wv; acc[5]  += a1.y * wv; acc[6]  += a1.z * wv; acc[7]  += a1.w * wv;
    acc[8]  += a2.x * wv; acc[9]  += a2.y * wv; acc[10] += a2.z * wv; acc[11] += a2.w * wv;
    acc[12] += a3.x * wv; acc[13] += a3.y * wv; acc[14] += a3.z * wv; acc[15] += a3.w * wv;
  }
  #pragma unroll
  for (int i = 0; i < 16; ++i) {
    int r = r0 + i;
    if (r < M) Y[(size_t)r * DD + tid] = acc[i];
  }
}

// ---------- 8-deep weighted gather-accumulate over one wave's segment ----------
// rv/wv hold (row, weight) for incidence c*64+lane; invalid lanes carry w=0, row=0.
__device__ __forceinline__ void gatherAcc(float4& acc, const float4* __restrict__ src4,
                                          const int (&rv)[4], const float (&wv)[4],
                                          int nc, int lane) {
  #pragma unroll
  for (int c = 0; c < 4; ++c) {
    int lim = nc - c * 64; if (lim > 64) lim = 64;
    for (int t = 0; t < lim; t += 8) {
      int   n0 = __shfl(rv[c], t + 0), n1 = __shfl(rv[c], t + 1);
      int   n2 = __shfl(rv[c], t + 2), n3 = __shfl(rv[c], t + 3);
      int   n4 = __shfl(rv[c], t + 4), n5 = __shfl(rv[c], t + 5);
      int   n6 = __shfl(rv[c], t + 6), n7 = __shfl(rv[c], t + 7);
      float w0 = __shfl(wv[c], t + 0), w1 = __shfl(wv[c], t + 1);
      float w2 = __shfl(wv[c], t + 2), w3 = __shfl(wv[c], t + 3);
      float w4 = __shfl(wv[c], t + 4), w5 = __shfl(wv[c], t + 5);
      float w6 = __shfl(wv[c], t + 6), w7 = __shfl(wv[c], t + 7);
      float4 a0 = src4[(size_t)n0 * 64 + lane];
      float4 a1 = src4[(size_t)n1 * 64 + lane];
      float4 a2 = src4[(size_t)n2 * 64 + lane];
      float4 a3 = src4[(size_t)n3 * 64 + lane];
      float4 a4 = src4[(size_t)n4 * 64 + lane];
      float4 a5 = src4[(size_t)n5 * 64 + lane];
      float4 a6 = src4[(size_t)n6 * 64 + lane];
      float4 a7 = src4[(size_t)n7 * 64 + lane];
      acc.x += w0*a0.x + w1*a1.x + w2*a2.x + w3*a3.x + w4*a4.x + w5*a5.x + w6*a6.x + w7*a7.x;
      acc.y += w0*a0.y + w1*a1.y + w2*a2.y + w3*a3.y + w4*a4.y + w5*a5.y + w6*a6.y + w7*a7.y;
      acc.z += w0*a0.z + w1*a1.z + w2*a2.z + w3*a3.z + w4*a4.z + w5*a5.z + w6*a6.z + w7*a7.z;
      acc.w += w0*a0.w + w1*a1.w + w2*a2.w + w3*a3.w + w4*a4.w + w5*a5.w + w6*a6.w + w7*a7.w;
    }
  }
}

// ---------- segment ops (wave per segment) ----------
// dst[s,:] = mean over CSR row of src[pay[j], :]
__global__ __launch_bounds__(256) void seg_mean_k(const int* __restrict__ offs,
                                                  const int* __restrict__ pay,
                                                  const float* __restrict__ src,
                                                  float* __restrict__ dst, int nseg) {
  int wid = (blockIdx.x * 256 + threadIdx.x) >> 6;
  int lane = threadIdx.x & 63;
  if (wid >= nseg) return;
  int beg = offs[wid], end = offs[wid + 1];
  int cnt = end - beg;
  int nc = cnt < 256 ? cnt : 256;
  int rv[4]; float wv[4];
  #pragma unroll
  for (int c = 0; c < 4; ++c) {
    int j = c * 64 + lane;
    if (j < nc) { rv[c] = pay[beg + j]; wv[c] = 1.f; }
    else        { rv[c] = 0;            wv[c] = 0.f; }
  }
  float4 acc = make_float4(0.f, 0.f, 0.f, 0.f);
  gatherAcc(acc, (const float4*)src, rv, wv, nc, lane);
  for (int j = 256; j < cnt; ++j) {   // overflow fallback (cold)
    int n = pay[beg + j];
    float4 a = ((const float4*)src)[(size_t)n * 64 + lane];
    acc.x += a.x; acc.y += a.y; acc.z += a.z; acc.w += a.w;
  }
  float inv = 1.f / (float)(cnt > 1 ? cnt : 1);
  float4 o; o.x = acc.x * inv; o.y = acc.y * inv; o.z = acc.z * inv; o.w = acc.w * inv;
  ((float4*)dst)[(size_t)wid * 64 + lane] = o;
}

// per-reaction: attention softmax over incidences + weighted node->edge aggregation.
// writes me (already /max(B,1)) and rstat[r] = {se, m, invS, 0} so out_k can rebuild w.
__global__ __launch_bounds__(256) void me_k(const int* __restrict__ offs,
                                            const int* __restrict__ nodeE,
                                            const float* __restrict__ stoE,
                                            const float* __restrict__ sn,
                                            const float* __restrict__ se,
                                            const float* __restrict__ xp,
                                            float* __restrict__ me,
                                            float4* __restrict__ rstat) {
  int wid = (blockIdx.x * 256 + threadIdx.x) >> 6;
  int lane = threadIdx.x & 63;
  if (wid >= N_RXN) return;
  int beg = offs[wid], end = offs[wid + 1];
  int cnt = end - beg;
  int nc = cnt < 256 ? cnt : 256;
  float ser = se[wid];
  int nv[4]; float wv[4];
  float lmax = -1e30f;
  #pragma unroll
  for (int c = 0; c < 4; ++c) {
    int j = c * 64 + lane;
    if (j < nc) {
      int n = nodeE[beg + j];
      float l = sn[n] + ser;
      l = (l >= 0.f) ? l : 0.2f * l;
      nv[c] = n; wv[c] = l;
      lmax = fmaxf(lmax, l);
    } else { nv[c] = 0; wv[c] = -1e30f; }
  }
  for (int j = 256 + lane; j < cnt; j += 64) {   // overflow (cold)
    float l = sn[nodeE[beg + j]] + ser;
    l = (l >= 0.f) ? l : 0.2f * l;
    lmax = fmaxf(lmax, l);
  }
  float m = waveMax(lmax);
  float s = 0.f;
  #pragma unroll
  for (int c = 0; c < 4; ++c) {
    if (c * 64 + lane < nc) { float e = expf(wv[c] - m); wv[c] = e; s += e; }
    else wv[c] = 0.f;
  }
  for (int j = 256 + lane; j < cnt; j += 64) {   // overflow (cold)
    float l = sn[nodeE[beg + j]] + ser;
    l = (l >= 0.f) ? l : 0.2f * l;
    s += expf(l - m);
  }
  s = waveSum(s);
  float invS = 1.f / (s + 1e-16f);
  #pragma unroll
  for (int c = 0; c < 4; ++c) {
    int j = c * 64 + lane;
    if (j < nc) wv[c] = stoE[beg + j] * wv[c] * invS;
  }
  if (lane == 0) rstat[wid] = make_float4(ser, m, invS, 0.f);
  float4 acc = make_float4(0.f, 0.f, 0.f, 0.f);
  gatherAcc(acc, (const float4*)xp, nv, wv, nc, lane);
  for (int j = 256; j < cnt; ++j) {   // overflow (cold)
    int n = nodeE[beg + j];
    float l = sn[n] + ser;
    l = (l >= 0.f) ? l : 0.2f * l;
    float w = stoE[beg + j] * expf(l - m) * invS;
    float4 a = ((const float4*)xp)[(size_t)n * 64 + lane];
    acc.x += w * a.x; acc.y += w * a.y; acc.z += w * a.z; acc.w += w * a.w;
  }
  float invB = 1.f / (float)(cnt > 1 ? cnt : 1);
  float4 o; o.x = acc.x * invB; o.y = acc.y * invB; o.z = acc.z * invB; o.w = acc.w * invB;
  ((float4*)me)[(size_t)wid * 64 + lane] = o;
}

// per-metabolite: edge->node aggregation + bias + tanh (+ skip + layernorm for layer 1)
template <bool LN>
__global__ __launch_bounds__(256) void out_k(const int* __restrict__ offs,
                                             const int* __restrict__ edgeN,
                                             const float* __restrict__ stoN,
                                             const float* __restrict__ sn,
                                             const float4* __restrict__ rstat,
                                             const float* __restrict__ me,
                                             const float* __restrict__ bias,
                                             const float* __restrict__ ln_g,
                                             const float* __restrict__ ln_b,
                                             float* __restrict__ cur) {
  int wid = (blockIdx.x * 256 + threadIdx.x) >> 6;
  int lane = threadIdx.x & 63;
  if (wid >= N_MET) return;
  int beg = offs[wid], end = offs[wid + 1];
  int cnt = end - beg;
  int nc = cnt < 256 ? cnt : 256;
  float sn_n = sn[wid];
  int rv[4]; float wv[4];
  #pragma unroll
  for (int c = 0; c < 4; ++c) {
    int j = c * 64 + lane;
    if (j < nc) {
      int r = edgeN[beg + j];
      float4 st = rstat[r];
      float l = sn_n + st.x;
      l = (l >= 0.f) ? l : 0.2f * l;
      rv[c] = r;
      wv[c] = stoN[beg + j] * expf(l - st.y) * st.z;
    } else { rv[c] = 0; wv[c] = 0.f; }
  }
  float4 acc = make_float4(0.f, 0.f, 0.f, 0.f);
  gatherAcc(acc, (const float4*)me, rv, wv, nc, lane);
  for (int j = 256; j < cnt; ++j) {   // overflow (cold)
    int r = edgeN[beg + j];
    float4 st = rstat[r];
    float l = sn_n + st.x;
    l = (l >= 0.f) ? l : 0.2f * l;
    float w = stoN[beg + j] * expf(l - st.y) * st.z;
    float4 a = ((const float4*)me)[(size_t)r * 64 + lane];
    acc.x += w * a.x; acc.y += w * a.y; acc.z += w * a.z; acc.w += w * a.w;
  }
  float invD = 1.f / (float)(cnt > 1 ? cnt : 1);
  float4 b4 = ((const float4*)bias)[lane];
  float4 o;
  o.x = tanhf(acc.x * invD + b4.x);
  o.y = tanhf(acc.y * invD + b4.y);
  o.z = tanhf(acc.z * invD + b4.z);
  o.w = tanhf(acc.w * invD + b4.w);
  float4* cur4 = (float4*)cur;
  if (!LN) {
    cur4[(size_t)wid * 64 + lane] = o;
    return;
  }
  float4 p = cur4[(size_t)wid * 64 + lane];
  float4 z; z.x = o.x + p.x; z.y = o.y + p.y; z.z = o.z + p.z; z.w = o.w + p.w;
  float mu = waveSum(z.x + z.y + z.z + z.w) * (1.f / 256.f);
  float4 zc; zc.x = z.x - mu; zc.y = z.y - mu; zc.z = z.z - mu; zc.w = z.w - mu;
  float var = waveSum(zc.x * zc.x + zc.y * zc.y + zc.z * zc.z + zc.w * zc.w) * (1.f / 256.f);
  float rs = 1.f / sqrtf(var + 1e-5f);
  float4 g4 = ((const float4*)ln_g)[lane];
  float4 be4 = ((const float4*)ln_b)[lane];
  float4 r;
  r.x = zc.x * rs * g4.x + be4.x;
  r.y = zc.y * rs * g4.y + be4.y;
  r.z = zc.z * rs * g4.z + be4.z;
  r.w = zc.w * rs * g4.w + be4.w;
  cur4[(size_t)wid * 64 + lane] = r;
}

// ---------- launcher ----------
extern "C" void kernel_launch(void* const* d_in, const int* in_sizes, int n_in,
                              void* d_out, int out_size, void* d_ws, size_t ws_size,
                              hipStream_t stream) {
  const int*   he_node = (const int*)d_in[0];
  const int*   he_edge = (const int*)d_in[1];
  const float* stoich  = (const float*)d_in[2];
  const float* gene_x  = (const float*)d_in[3];
  const int*   rtg_rxn = (const int*)d_in[4];
  const int*   rtg_gene= (const int*)d_in[5];
  const float* emb     = (const float*)d_in[6];
  const float* W0      = (const float*)d_in[7];
  const float* We0     = (const float*)d_in[8];
  const float* att0    = (const float*)d_in[9];
  const float* b0      = (const float*)d_in[10];
  const float* W1      = (const float*)d_in[11];
  const float* We1     = (const float*)d_in[12];
  const float* att1    = (const float*)d_in[13];
  const float* b1      = (const float*)d_in[14];
  const float* ln_g    = (const float*)d_in[15];
  const float* ln_b    = (const float*)d_in[16];
  float* out = (float*)d_out;

  char* base = (char*)d_ws;
  size_t off = 0;
  auto carve = [&](size_t bytes) -> char* {
    char* p = base + off;
    off += (bytes + 255) & ~(size_t)255;
    return p;
  };
  float*  met     = (float*)carve((size_t)N_MET  * DD * 4);
  float*  rxn_emb = (float*)carve((size_t)N_RXN  * DD * 4);
  float*  xp      = (float*)carve((size_t)N_MET  * DD * 4);
  float*  me      = (float*)carve((size_t)N_RXN  * DD * 4);
  float*  cur     = (float*)carve((size_t)N_MET  * DD * 4);
  float*  rxnf    = (float*)carve((size_t)N_RXN  * DD * 4);
  float*  sn      = (float*)carve((size_t)N_MET * 4);
  float*  se      = (float*)carve((size_t)N_RXN * 4);
  float*  ve0     = (float*)carve(DD * 4);
  float*  ve1     = (float*)carve(DD * 4);
  float4* rstat   = (float4*)carve((size_t)N_RXN * 16);
  int* cnts = (int*)carve((size_t)(N_RXN + N_MET + N_RXN + N_GENE) * 4);
  int* cntE = cnts;
  int* cntN = cntE + N_RXN;
  int* cntR = cntN + N_MET;
  int* cntG = cntR + N_RXN;
  int*   offsE = (int*)carve((N_RXN + 1) * 4);
  int*   curE  = (int*)carve(N_RXN * 4);
  int*   nodeE = (int*)carve((size_t)NE * 4);
  float* stoE  = (float*)carve((size_t)NE * 4);
  int*   offsN = (int*)carve((N_MET + 1) * 4);
  int*   curN  = (int*)carve(N_MET * 4);
  int*   edgeN = (int*)carve((size_t)NE * 4);
  float* stoN  = (float*)carve((size_t)NE * 4);
  int*   offsR = (int*)carve((N_RXN + 1) * 4);
  int*   curR  = (int*)carve(N_RXN * 4);
  int*   geneR = (int*)carve((size_t)NP * 4);
  int*   offsG = (int*)carve((N_GENE + 1) * 4);
  int*   curG  = (int*)carve(N_GENE * 4);
  int*   rxnG  = (int*)carve((size_t)NP * 4);

  // CSR build
  hipMemsetAsync(cnts, 0, (size_t)(N_RXN + N_MET + N_RXN + N_GENE) * 4, stream);
  hist2_k<<<(NE + 255) / 256, 256, 0, stream>>>(he_edge, he_node, NE, cntE, cntN);
  hist2_k<<<(NP + 255) / 256, 256, 0, stream>>>(rtg_rxn, rtg_gene, NP, cntR, cntG);
  scan4_k<<<4, 1024, 0, stream>>>(cntE, N_RXN, offsE, curE,
                                  cntN, N_MET, offsN, curN,
                                  cntR, N_RXN, offsR, curR,
                                  cntG, N_GENE, offsG, curG);
  fill_he_k<<<(NE + 255) / 256, 256, 0, stream>>>(he_node, he_edge, stoich,
                                                  curE, nodeE, stoE, curN, edgeN, stoN);
  fill_rtg_k<<<(NP + 255) / 256, 256, 0, stream>>>(rtg_rxn, rtg_gene,
                                                   curR, geneR, curG, rxnG);

  // preprocessing
  renorm_k<<<(N_MET + 3) / 4, 256, 0, stream>>>(emb, met);
  seg_mean_k<<<(N_RXN + 3) / 4, 256, 0, stream>>>(offsR, geneR, gene_x, rxn_emb, N_RXN);
  rowdot_k<<<(256 + 3) / 4, 256, 0, stream>>>(We0, att0 + DD, ve0, 256);
  rowdot_k<<<(256 + 3) / 4, 256, 0, stream>>>(We1, att1 + DD, ve1, 256);

  // layer 0
  gemm256_k<<<(N_MET + 15) / 16, 256, 0, stream>>>(met, W0, xp, N_MET);
  rowdot_k<<<(N_MET + 3) / 4, 256, 0, stream>>>(xp, att0, sn, N_MET);
  rowdot_k<<<(N_RXN + 3) / 4, 256, 0, stream>>>(rxn_emb, ve0, se, N_RXN);
  me_k<<<(N_RXN + 3) / 4, 256, 0, stream>>>(offsE, nodeE, stoE, sn, se, xp, me, rstat);
  out_k<false><<<(N_MET + 3) / 4, 256, 0, stream>>>(offsN, edgeN, stoN, sn, rstat, me, b0,
                                                    nullptr, nullptr, cur);

  // layer 1 (skip + layernorm fused)
  gemm256_k<<<(N_MET + 15) / 16, 256, 0, stream>>>(cur, W1, xp, N_MET);
  rowdot_k<<<(N_MET + 3) / 4, 256, 0, stream>>>(xp, att1, sn, N_MET);
  rowdot_k<<<(N_RXN + 3) / 4, 256, 0, stream>>>(rxn_emb, ve1, se, N_RXN);
  me_k<<<(N_RXN + 3) / 4, 256, 0, stream>>>(offsE, nodeE, stoE, sn, se, xp, me, rstat);
  out_k<true><<<(N_MET + 3) / 4, 256, 0, stream>>>(offsN, edgeN, stoN, sn, rstat, me, b1,
                                                   ln_g, ln_b, cur);

  // final readout
  seg_mean_k<<<(N_RXN + 3) / 4, 256, 0, stream>>>(offsE, nodeE, cur, rxnf, N_RXN);
  seg_mean_k<<<(N_GENE + 3) / 4, 256, 0, stream>>>(offsG, rxnG, rxnf, out, N_GENE);
}

// Round 3
// 303.174 us; speedup vs baseline: 2.5300x; 1.0388x over previous
//
#include <hip/hip_runtime.h>
#include <math.h>

#define DD 256
static constexpr int N_MET  = 2534;
static constexpr int N_RXN  = 4881;
static constexpr int N_GENE = 6607;
static constexpr int NE     = 262144;
static constexpr int NP     = 131072;

// ---------- wave reductions (64 lanes) ----------
__device__ __forceinline__ float waveSum(float v) {
  #pragma unroll
  for (int o = 32; o > 0; o >>= 1) v += __shfl_xor(v, o, 64);
  return v;
}
__device__ __forceinline__ float waveMax(float v) {
  #pragma unroll
  for (int o = 32; o > 0; o >>= 1) v = fmaxf(v, __shfl_xor(v, o, 64));
  return v;
}

// ---------- CSR building ----------
__global__ void hist_all_k(const int* __restrict__ he_edge, const int* __restrict__ he_node,
                           const int* __restrict__ rtg_rxn, const int* __restrict__ rtg_gene,
                           int* cntE, int* cntN, int* cntR, int* cntG) {
  int i = blockIdx.x * blockDim.x + threadIdx.x;
  if (i < NE) { atomicAdd(&cntE[he_edge[i]], 1); atomicAdd(&cntN[he_node[i]], 1); }
  if (i < NP) { atomicAdd(&cntR[rtg_rxn[i]], 1); atomicAdd(&cntG[rtg_gene[i]], 1); }
}

// packed payload fill: one 8B scatter per CSR side instead of two 4B scatters
__global__ void fill_all_k(const int* __restrict__ he_node, const int* __restrict__ he_edge,
                           const float* __restrict__ stoich,
                           const int* __restrict__ rtg_rxn, const int* __restrict__ rtg_gene,
                           int* curE, int2* __restrict__ payE,
                           int* curN, int2* __restrict__ payN,
                           int* curR, int* __restrict__ geneR,
                           int* curG, int* __restrict__ rxnG) {
  int i = blockIdx.x * blockDim.x + threadIdx.x;
  if (i < NE) {
    int n = he_node[i], e = he_edge[i];
    int st = __float_as_int(stoich[i]);
    int pa = atomicAdd(&curE[e], 1); payE[pa] = make_int2(n, st);
    int pb = atomicAdd(&curN[n], 1); payN[pb] = make_int2(e, st);
  }
  if (i < NP) {
    int r = rtg_rxn[i], g = rtg_gene[i];
    int pa = atomicAdd(&curR[r], 1); geneR[pa] = g;
    int pb = atomicAdd(&curG[g], 1); rxnG[pb] = r;
  }
}

// exclusive scan of 4 arrays (n <= 8192 each), one block per array
__global__ void scan4_k(const int* c0, int n0, int* o0, int* u0,
                        const int* c1, int n1, int* o1, int* u1,
                        const int* c2, int n2, int* o2, int* u2,
                        const int* c3, int n3, int* o3, int* u3) {
  const int* cnt; int n; int* offs; int* cur;
  if      (blockIdx.x == 0) { cnt = c0; n = n0; offs = o0; cur = u0; }
  else if (blockIdx.x == 1) { cnt = c1; n = n1; offs = o1; cur = u1; }
  else if (blockIdx.x == 2) { cnt = c2; n = n2; offs = o2; cur = u2; }
  else                      { cnt = c3; n = n3; offs = o3; cur = u3; }
  __shared__ int part[1024];
  int tid = threadIdx.x;
  int base = tid * 8;
  int v[8]; int s = 0;
  #pragma unroll
  for (int j = 0; j < 8; ++j) { int x = (base + j < n) ? cnt[base + j] : 0; v[j] = x; s += x; }
  part[tid] = s;
  __syncthreads();
  for (int o = 1; o < 1024; o <<= 1) {
    int t = (tid >= o) ? part[tid - o] : 0;
    __syncthreads();
    part[tid] += t;
    __syncthreads();
  }
  int ex = part[tid] - s;
  #pragma unroll
  for (int j = 0; j < 8; ++j) {
    if (base + j < n) { offs[base + j] = ex; cur[base + j] = ex; ex += v[j]; }
  }
  if (tid == 1023) offs[n] = part[1023];
}

// ---------- small dense ops ----------
// ve{0,1}[r] = dot(We{0,1}[r,:], att{0,1}[DD:]) — 512 waves total
__global__ __launch_bounds__(256) void vedot_k(const float* __restrict__ We0,
                                               const float* __restrict__ att0,
                                               const float* __restrict__ We1,
                                               const float* __restrict__ att1,
                                               float* __restrict__ ve0,
                                               float* __restrict__ ve1) {
  int wid = (blockIdx.x * 256 + threadIdx.x) >> 6;
  int lane = threadIdx.x & 63;
  if (wid >= 512) return;
  const float* We = (wid < 256) ? We0 : We1;
  const float* at = (wid < 256) ? att0 : att1;
  int r = wid & 255;
  float4 a = ((const float4*)(We + (size_t)r * DD))[lane];
  float4 v = ((const float4*)(at + DD))[lane];
  float s = waveSum(a.x * v.x + a.y * v.y + a.z * v.z + a.w * v.w);
  if (lane == 0) ((wid < 256) ? ve0 : ve1)[r] = s;
}

// se{0,1}[r] = dot(rxn_emb[r,:], ve{0,1}) — one row read, two dots
__global__ __launch_bounds__(256) void se_dual_k(const float* __restrict__ rxn_emb,
                                                 const float* __restrict__ ve0,
                                                 const float* __restrict__ ve1,
                                                 float* __restrict__ se0,
                                                 float* __restrict__ se1) {
  int wid = (blockIdx.x * 256 + threadIdx.x) >> 6;
  int lane = threadIdx.x & 63;
  if (wid >= N_RXN) return;
  float4 a  = ((const float4*)rxn_emb)[(size_t)wid * 64 + lane];
  float4 v0 = ((const float4*)ve0)[lane];
  float4 v1 = ((const float4*)ve1)[lane];
  float s0 = waveSum(a.x * v0.x + a.y * v0.y + a.z * v0.z + a.w * v0.w);
  float s1 = waveSum(a.x * v1.x + a.y * v1.y + a.z * v1.z + a.w * v1.w);
  if (lane == 0) { se0[wid] = s0; se1[wid] = s1; }
}

// Y = X @ W (K=N=256), optional input row-renorm (max_norm=1), fused sn[r]=dot(Y[r,:],att).
// 16 rows per block, 256 threads (one output column each).
template <bool RENORM>
__global__ __launch_bounds__(256) void gemm256_k(const float* __restrict__ X,
                                                 const float* __restrict__ W,
                                                 const float* __restrict__ att,
                                                 float* __restrict__ Y,
                                                 float* __restrict__ sn, int M) {
  __shared__ float Xs[256][20];
  __shared__ float red[4][16];
  __shared__ float scl[16];
  int tid = threadIdx.x;
  int w = tid >> 6, lane = tid & 63;
  int r0 = blockIdx.x * 16;
  float xv[16];
  #pragma unroll
  for (int i = 0; i < 16; ++i) {
    int r = r0 + i;
    xv[i] = (r < M) ? X[(size_t)r * DD + tid] : 0.f;
  }
  if (RENORM) {
    #pragma unroll
    for (int i = 0; i < 16; ++i) {
      float v = waveSum(xv[i] * xv[i]);
      if (lane == 0) red[w][i] = v;
    }
    __syncthreads();
    if (tid < 16) {
      float t = red[0][tid] + red[1][tid] + red[2][tid] + red[3][tid];
      scl[tid] = fminf(1.f, 1.f / (sqrtf(t) + 1e-12f));
    }
    __syncthreads();
    #pragma unroll
    for (int i = 0; i < 16; ++i) xv[i] *= scl[i];
  }
  #pragma unroll
  for (int i = 0; i < 16; ++i) Xs[tid][i] = xv[i];
  __syncthreads();
  float acc[16];
  #pragma unroll
  for (int i = 0; i < 16; ++i) acc[i] = 0.f;
  const float* wp = W + tid;
  #pragma unroll 8
  for (int k = 0; k < 256; ++k) {
    float wv = wp[(size_t)k * DD];
    const float4* xr = reinterpret_cast<const float4*>(&Xs[k][0]);
    float4 a0 = xr[0], a1 = xr[1], a2 = xr[2], a3 = xr[3];
    acc[0]  += a0.x * wv; acc[1]  += a0.y * wv; acc[2]  += a0.z * wv; acc[3]  += a0.w * wv;
    acc[4]  += a1.x * wv; acc[5]  += a1.y * wv; acc[6]  += a1.z * wv; acc[7]  += a1.w * wv;
    acc[8]  += a2.x * wv; acc[9]  += a2.y * wv; acc[10] += a2.z * wv; acc[11] += a2.w * wv;
    acc[12] += a3.x * wv; acc[13] += a3.y * wv; acc[14] += a3.z * wv; acc[15] += a3.w * wv;
  }
  #pragma unroll
  for (int i = 0; i < 16; ++i) {
    int r = r0 + i;
    if (r < M) Y[(size_t)r * DD + tid] = acc[i];
  }
  // fused sn[r] = sum_col Y[r,col] * att[col]
  float av = att[tid];
  __syncthreads();
  #pragma unroll
  for (int i = 0; i < 16; ++i) {
    float v = waveSum(acc[i] * av);
    if (lane == 0) red[w][i] = v;
  }
  __syncthreads();
  if (tid < 16) {
    int r = r0 + tid;
    if (r < M) sn[r] = red[0][tid] + red[1][tid] + red[2][tid] + red[3][tid];
  }
}

// ---------- 16-deep weighted gather-accumulate over one wave's segment ----------
// rv/wv hold (row, weight) for incidence c*64+lane; invalid lanes carry w=0, row=0.
__device__ __forceinline__ void gatherAcc(float4& acc, const float4* __restrict__ src4,
                                          const int (&rv)[4], const float (&wv)[4],
                                          int nc, int lane) {
  #pragma unroll
  for (int c = 0; c < 4; ++c) {
    int lim = nc - c * 64; if (lim > 64) lim = 64;
    for (int t = 0; t < lim; t += 16) {
      float4 a[16]; float w[16];
      #pragma unroll
      for (int q = 0; q < 16; ++q) {
        int   n = __shfl(rv[c], t + q);
        w[q]    = __shfl(wv[c], t + q);
        a[q]    = src4[(size_t)n * 64 + lane];
      }
      #pragma unroll
      for (int q = 0; q < 16; ++q) {
        acc.x += w[q] * a[q].x; acc.y += w[q] * a[q].y;
        acc.z += w[q] * a[q].z; acc.w += w[q] * a[q].w;
      }
    }
  }
}

// ---------- segment ops (wave per segment) ----------
// dst[s,:] = mean over CSR row of src[pay[j*STRIDE], :]
template <int STRIDE>
__global__ __launch_bounds__(256) void seg_mean_k(const int* __restrict__ offs,
                                                  const int* __restrict__ pay,
                                                  const float* __restrict__ src,
                                                  float* __restrict__ dst, int nseg) {
  int wid = (blockIdx.x * 256 + threadIdx.x) >> 6;
  int lane = threadIdx.x & 63;
  if (wid >= nseg) return;
  int beg = offs[wid], end = offs[wid + 1];
  int cnt = end - beg;
  int nc = cnt < 256 ? cnt : 256;
  int rv[4]; float wv[4];
  #pragma unroll
  for (int c = 0; c < 4; ++c) {
    int j = c * 64 + lane;
    if (j < nc) { rv[c] = pay[(size_t)(beg + j) * STRIDE]; wv[c] = 1.f; }
    else        { rv[c] = 0;                               wv[c] = 0.f; }
  }
  float4 acc = make_float4(0.f, 0.f, 0.f, 0.f);
  gatherAcc(acc, (const float4*)src, rv, wv, nc, lane);
  for (int j = 256; j < cnt; ++j) {   // overflow fallback (cold)
    int n = pay[(size_t)(beg + j) * STRIDE];
    float4 a = ((const float4*)src)[(size_t)n * 64 + lane];
    acc.x += a.x; acc.y += a.y; acc.z += a.z; acc.w += a.w;
  }
  float inv = 1.f / (float)(cnt > 1 ? cnt : 1);
  float4 o; o.x = acc.x * inv; o.y = acc.y * inv; o.z = acc.z * inv; o.w = acc.w * inv;
  ((float4*)dst)[(size_t)wid * 64 + lane] = o;
}

// per-reaction: attention softmax over incidences + weighted node->edge aggregation.
// writes me (already /max(B,1)) and rstat[r] = {se, m, invS, 0} so out_k can rebuild w.
__global__ __launch_bounds__(256) void me_k(const int* __restrict__ offs,
                                            const int2* __restrict__ payE,
                                            const float* __restrict__ sn,
                                            const float* __restrict__ se,
                                            const float* __restrict__ xp,
                                            float* __restrict__ me,
                                            float4* __restrict__ rstat) {
  int wid = (blockIdx.x * 256 + threadIdx.x) >> 6;
  int lane = threadIdx.x & 63;
  if (wid >= N_RXN) return;
  int beg = offs[wid], end = offs[wid + 1];
  int cnt = end - beg;
  int nc = cnt < 256 ? cnt : 256;
  float ser = se[wid];
  int nv[4]; float wv[4]; float stv[4];
  float lmax = -1e30f;
  #pragma unroll
  for (int c = 0; c < 4; ++c) {
    int j = c * 64 + lane;
    if (j < nc) {
      int2 p = payE[beg + j];
      float l = sn[p.x] + ser;
      l = (l >= 0.f) ? l : 0.2f * l;
      nv[c] = p.x; wv[c] = l; stv[c] = __int_as_float(p.y);
      lmax = fmaxf(lmax, l);
    } else { nv[c] = 0; wv[c] = -1e30f; stv[c] = 0.f; }
  }
  for (int j = 256 + lane; j < cnt; j += 64) {   // overflow (cold)
    int2 p = payE[beg + j];
    float l = sn[p.x] + ser;
    l = (l >= 0.f) ? l : 0.2f * l;
    lmax = fmaxf(lmax, l);
  }
  float m = waveMax(lmax);
  float s = 0.f;
  #pragma unroll
  for (int c = 0; c < 4; ++c) {
    if (c * 64 + lane < nc) { float e = expf(wv[c] - m); wv[c] = e; s += e; }
    else wv[c] = 0.f;
  }
  for (int j = 256 + lane; j < cnt; j += 64) {   // overflow (cold)
    int2 p = payE[beg + j];
    float l = sn[p.x] + ser;
    l = (l >= 0.f) ? l : 0.2f * l;
    s += expf(l - m);
  }
  s = waveSum(s);
  float invS = 1.f / (s + 1e-16f);
  #pragma unroll
  for (int c = 0; c < 4; ++c) {
    if (c * 64 + lane < nc) wv[c] = stv[c] * wv[c] * invS;
  }
  if (lane == 0) rstat[wid] = make_float4(ser, m, invS, 0.f);
  float4 acc = make_float4(0.f, 0.f, 0.f, 0.f);
  gatherAcc(acc, (const float4*)xp, nv, wv, nc, lane);
  for (int j = 256; j < cnt; ++j) {   // overflow (cold)
    int2 p = payE[beg + j];
    float l = sn[p.x] + ser;
    l = (l >= 0.f) ? l : 0.2f * l;
    float w = __int_as_float(p.y) * expf(l - m) * invS;
    float4 a = ((const float4*)xp)[(size_t)p.x * 64 + lane];
    acc.x += w * a.x; acc.y += w * a.y; acc.z += w * a.z; acc.w += w * a.w;
  }
  float invB = 1.f / (float)(cnt > 1 ? cnt : 1);
  float4 o; o.x = acc.x * invB; o.y = acc.y * invB; o.z = acc.z * invB; o.w = acc.w * invB;
  ((float4*)me)[(size_t)wid * 64 + lane] = o;
}

// per-metabolite: edge->node aggregation + bias + tanh (+ skip + layernorm for layer 1)
template <bool LN>
__global__ __launch_bounds__(256) void out_k(const int* __restrict__ offs,
                                             const int2* __restrict__ payN,
                                             const float* __restrict__ sn,
                                             const float4* __restrict__ rstat,
                                             const float* __restrict__ me,
                                             const float* __restrict__ bias,
                                             const float* __restrict__ ln_g,
                                             const float* __restrict__ ln_b,
                                             float* __restrict__ cur) {
  int wid = (blockIdx.x * 256 + threadIdx.x) >> 6;
  int lane = threadIdx.x & 63;
  if (wid >= N_MET) return;
  int beg = offs[wid], end = offs[wid + 1];
  int cnt = end - beg;
  int nc = cnt < 256 ? cnt : 256;
  float sn_n = sn[wid];
  int rv[4]; float wv[4];
  #pragma unroll
  for (int c = 0; c < 4; ++c) {
    int j = c * 64 + lane;
    if (j < nc) {
      int2 p = payN[beg + j];
      float4 st = rstat[p.x];
      float l = sn_n + st.x;
      l = (l >= 0.f) ? l : 0.2f * l;
      rv[c] = p.x;
      wv[c] = __int_as_float(p.y) * expf(l - st.y) * st.z;
    } else { rv[c] = 0; wv[c] = 0.f; }
  }
  float4 acc = make_float4(0.f, 0.f, 0.f, 0.f);
  gatherAcc(acc, (const float4*)me, rv, wv, nc, lane);
  for (int j = 256; j < cnt; ++j) {   // overflow (cold)
    int2 p = payN[beg + j];
    float4 st = rstat[p.x];
    float l = sn_n + st.x;
    l = (l >= 0.f) ? l : 0.2f * l;
    float w = __int_as_float(p.y) * expf(l - st.y) * st.z;
    float4 a = ((const float4*)me)[(size_t)p.x * 64 + lane];
    acc.x += w * a.x; acc.y += w * a.y; acc.z += w * a.z; acc.w += w * a.w;
  }
  float invD = 1.f / (float)(cnt > 1 ? cnt : 1);
  float4 b4 = ((const float4*)bias)[lane];
  float4 o;
  o.x = tanhf(acc.x * invD + b4.x);
  o.y = tanhf(acc.y * invD + b4.y);
  o.z = tanhf(acc.z * invD + b4.z);
  o.w = tanhf(acc.w * invD + b4.w);
  float4* cur4 = (float4*)cur;
  if (!LN) {
    cur4[(size_t)wid * 64 + lane] = o;
    return;
  }
  float4 p = cur4[(size_t)wid * 64 + lane];
  float4 z; z.x = o.x + p.x; z.y = o.y + p.y; z.z = o.z + p.z; z.w = o.w + p.w;
  float mu = waveSum(z.x + z.y + z.z + z.w) * (1.f / 256.f);
  float4 zc; zc.x = z.x - mu; zc.y = z.y - mu; zc.z = z.z - mu; zc.w = z.w - mu;
  float var = waveSum(zc.x * zc.x + zc.y * zc.y + zc.z * zc.z + zc.w * zc.w) * (1.f / 256.f);
  float rs = 1.f / sqrtf(var + 1e-5f);
  float4 g4 = ((const float4*)ln_g)[lane];
  float4 be4 = ((const float4*)ln_b)[lane];
  float4 r;
  r.x = zc.x * rs * g4.x + be4.x;
  r.y = zc.y * rs * g4.y + be4.y;
  r.z = zc.z * rs * g4.z + be4.z;
  r.w = zc.w * rs * g4.w + be4.w;
  cur4[(size_t)wid * 64 + lane] = r;
}

// ---------- launcher ----------
extern "C" void kernel_launch(void* const* d_in, const int* in_sizes, int n_in,
                              void* d_out, int out_size, void* d_ws, size_t ws_size,
                              hipStream_t stream) {
  const int*   he_node = (const int*)d_in[0];
  const int*   he_edge = (const int*)d_in[1];
  const float* stoich  = (const float*)d_in[2];
  const float* gene_x  = (const float*)d_in[3];
  const int*   rtg_rxn = (const int*)d_in[4];
  const int*   rtg_gene= (const int*)d_in[5];
  const float* emb     = (const float*)d_in[6];
  const float* W0      = (const float*)d_in[7];
  const float* We0     = (const float*)d_in[8];
  const float* att0    = (const float*)d_in[9];
  const float* b0      = (const float*)d_in[10];
  const float* W1      = (const float*)d_in[11];
  const float* We1     = (const float*)d_in[12];
  const float* att1    = (const float*)d_in[13];
  const float* att1_hi = att1;  // unused alias
  const float* b1      = (const float*)d_in[14];
  const float* ln_g    = (const float*)d_in[15];
  const float* ln_b    = (const float*)d_in[16];
  float* out = (float*)d_out;
  (void)att1_hi;

  char* base = (char*)d_ws;
  size_t off = 0;
  auto carve = [&](size_t bytes) -> char* {
    char* p = base + off;
    off += (bytes + 255) & ~(size_t)255;
    return p;
  };
  float*  rxn_emb = (float*)carve((size_t)N_RXN  * DD * 4);
  float*  xp      = (float*)carve((size_t)N_MET  * DD * 4);
  float*  me      = (float*)carve((size_t)N_RXN  * DD * 4);
  float*  cur     = (float*)carve((size_t)N_MET  * DD * 4);
  float*  rxnf    = (float*)carve((size_t)N_RXN  * DD * 4);
  float*  sn      = (float*)carve((size_t)N_MET * 4);
  float*  se0     = (float*)carve((size_t)N_RXN * 4);
  float*  se1     = (float*)carve((size_t)N_RXN * 4);
  float*  ve0     = (float*)carve(DD * 4);
  float*  ve1     = (float*)carve(DD * 4);
  float4* rstat   = (float4*)carve((size_t)N_RXN * 16);
  int* cnts = (int*)carve((size_t)(N_RXN + N_MET + N_RXN + N_GENE) * 4);
  int* cntE = cnts;
  int* cntN = cntE + N_RXN;
  int* cntR = cntN + N_MET;
  int* cntG = cntR + N_RXN;
  int*  offsE = (int*)carve((N_RXN + 1) * 4);
  int*  curE  = (int*)carve(N_RXN * 4);
  int2* payE  = (int2*)carve((size_t)NE * 8);
  int*  offsN = (int*)carve((N_MET + 1) * 4);
  int*  curN  = (int*)carve(N_MET * 4);
  int2* payN  = (int2*)carve((size_t)NE * 8);
  int*  offsR = (int*)carve((N_RXN + 1) * 4);
  int*  curR  = (int*)carve(N_RXN * 4);
  int*  geneR = (int*)carve((size_t)NP * 4);
  int*  offsG = (int*)carve((N_GENE + 1) * 4);
  int*  curG  = (int*)carve(N_GENE * 4);
  int*  rxnG  = (int*)carve((size_t)NP * 4);

  // CSR build
  hipMemsetAsync(cnts, 0, (size_t)(N_RXN + N_MET + N_RXN + N_GENE) * 4, stream);
  hist_all_k<<<(NE + 255) / 256, 256, 0, stream>>>(he_edge, he_node, rtg_rxn, rtg_gene,
                                                   cntE, cntN, cntR, cntG);
  scan4_k<<<4, 1024, 0, stream>>>(cntE, N_RXN, offsE, curE,
                                  cntN, N_MET, offsN, curN,
                                  cntR, N_RXN, offsR, curR,
                                  cntG, N_GENE, offsG, curG);
  fill_all_k<<<(NE + 255) / 256, 256, 0, stream>>>(he_node, he_edge, stoich,
                                                   rtg_rxn, rtg_gene,
                                                   curE, payE, curN, payN,
                                                   curR, geneR, curG, rxnG);

  // preprocessing
  seg_mean_k<1><<<(N_RXN + 3) / 4, 256, 0, stream>>>(offsR, geneR, gene_x, rxn_emb, N_RXN);
  vedot_k<<<2, 256, 0, stream>>>(We0, att0, We1, att1, ve0, ve1);
  se_dual_k<<<(N_RXN + 3) / 4, 256, 0, stream>>>(rxn_emb, ve0, ve1, se0, se1);

  // layer 0 (renorm fused into GEMM staging; sn fused into GEMM epilogue)
  gemm256_k<true><<<(N_MET + 15) / 16, 256, 0, stream>>>(emb, W0, att0, xp, sn, N_MET);
  me_k<<<(N_RXN + 3) / 4, 256, 0, stream>>>(offsE, payE, sn, se0, xp, me, rstat);
  out_k<false><<<(N_MET + 3) / 4, 256, 0, stream>>>(offsN, payN, sn, rstat, me, b0,
                                                    nullptr, nullptr, cur);

  // layer 1 (skip + layernorm fused)
  gemm256_k<false><<<(N_MET + 15) / 16, 256, 0, stream>>>(cur, W1, att1, xp, sn, N_MET);
  me_k<<<(N_RXN + 3) / 4, 256, 0, stream>>>(offsE, payE, sn, se1, xp, me, rstat);
  out_k<true><<<(N_MET + 3) / 4, 256, 0, stream>>>(offsN, payN, sn, rstat, me, b1,
                                                   ln_g, ln_b, cur);

  // final readout
  seg_mean_k<2><<<(N_RXN + 3) / 4, 256, 0, stream>>>(offsE, (const int*)payE, cur, rxnf, N_RXN);
  seg_mean_k<1><<<(N_GENE + 3) / 4, 256, 0, stream>>>(offsG, rxnG, rxnf, out, N_GENE);
}

// Round 4
// 280.739 us; speedup vs baseline: 2.7322x; 1.0799x over previous
//
#include <hip/hip_runtime.h>
#include <math.h>

#define DD 256
static constexpr int N_MET  = 2534;
static constexpr int N_RXN  = 4881;
static constexpr int N_GENE = 6607;
static constexpr int NE     = 262144;
static constexpr int NP     = 131072;

// ---------- wave reductions (64 lanes) ----------
__device__ __forceinline__ float waveSum(float v) {
  #pragma unroll
  for (int o = 32; o > 0; o >>= 1) v += __shfl_xor(v, o, 64);
  return v;
}
__device__ __forceinline__ float waveMax(float v) {
  #pragma unroll
  for (int o = 32; o > 0; o >>= 1) v = fmaxf(v, __shfl_xor(v, o, 64));
  return v;
}

// ---------- K1: hist (1024 blocks) + vedot (128 blocks) ----------
// vedot: u{0,1}[r] = dot(We{0,1}[r,:], att{0,1}[DD:2DD]) for r in [0,256) each.
__global__ __launch_bounds__(256) void hist_vedot_k(
    const int* __restrict__ he_edge, const int* __restrict__ he_node,
    const int* __restrict__ rtg_rxn, const int* __restrict__ rtg_gene,
    int* cntE, int* cntN, int* cntR, int* cntG,
    const float* __restrict__ We0, const float* __restrict__ att0,
    const float* __restrict__ We1, const float* __restrict__ att1,
    float* __restrict__ ve0, float* __restrict__ ve1) {
  int blk = blockIdx.x, tid = threadIdx.x;
  if (blk < 128) {
    // vedot: 512 waves total
    int wid = blk * 4 + (tid >> 6);
    int lane = tid & 63;
    const float* We = (wid < 256) ? We0 : We1;
    const float* at = (wid < 256) ? att0 : att1;
    int r = wid & 255;
    float4 a = ((const float4*)(We + (size_t)r * DD))[lane];
    float4 v = ((const float4*)(at + DD))[lane];
    float s = waveSum(a.x * v.x + a.y * v.y + a.z * v.z + a.w * v.w);
    if (lane == 0) ((wid < 256) ? ve0 : ve1)[r] = s;
  } else {
    int i = (blk - 128) * 256 + tid;
    if (i < NE) { atomicAdd(&cntE[he_edge[i]], 1); atomicAdd(&cntN[he_node[i]], 1); }
    if (i < NP) { atomicAdd(&cntR[rtg_rxn[i]], 1); atomicAdd(&cntG[rtg_gene[i]], 1); }
  }
}

// ---------- K2: scan4 (blocks 0-3, 1024 thr) + gdot (blocks 4.., 16 waves each) ----------
__global__ __launch_bounds__(1024) void scan_gdot_k(
    const int* c0, int n0, int* o0, int* u0,
    const int* c1, int n1, int* o1, int* u1,
    const int* c2, int n2, int* o2, int* u2,
    const int* c3, int n3, int* o3, int* u3,
    const float* __restrict__ gene_x,
    const float* __restrict__ ve0, const float* __restrict__ ve1,
    float* __restrict__ gdot0, float* __restrict__ gdot1) {
  int blk = blockIdx.x;
  if (blk < 4) {
    const int* cnt; int n; int* offs; int* cur;
    if      (blk == 0) { cnt = c0; n = n0; offs = o0; cur = u0; }
    else if (blk == 1) { cnt = c1; n = n1; offs = o1; cur = u1; }
    else if (blk == 2) { cnt = c2; n = n2; offs = o2; cur = u2; }
    else               { cnt = c3; n = n3; offs = o3; cur = u3; }
    __shared__ int part[1024];
    int tid = threadIdx.x;
    int base = tid * 8;
    int v[8]; int s = 0;
    #pragma unroll
    for (int j = 0; j < 8; ++j) { int x = (base + j < n) ? cnt[base + j] : 0; v[j] = x; s += x; }
    part[tid] = s;
    __syncthreads();
    for (int o = 1; o < 1024; o <<= 1) {
      int t = (tid >= o) ? part[tid - o] : 0;
      __syncthreads();
      part[tid] += t;
      __syncthreads();
    }
    int ex = part[tid] - s;
    #pragma unroll
    for (int j = 0; j < 8; ++j) {
      if (base + j < n) { offs[base + j] = ex; cur[base + j] = ex; ex += v[j]; }
    }
    if (tid == 1023) offs[n] = part[1023];
  } else {
    // gdot: per-gene scalar dots against ve0/ve1
    int wid = ((blk - 4) * 1024 + threadIdx.x) >> 6;
    int lane = threadIdx.x & 63;
    if (wid >= N_GENE) return;
    float4 a  = ((const float4*)gene_x)[(size_t)wid * 64 + lane];
    float4 v0 = ((const float4*)ve0)[lane];
    float4 v1 = ((const float4*)ve1)[lane];
    float s0 = waveSum(a.x * v0.x + a.y * v0.y + a.z * v0.z + a.w * v0.w);
    float s1 = waveSum(a.x * v1.x + a.y * v1.y + a.z * v1.z + a.w * v1.w);
    if (lane == 0) { gdot0[wid] = s0; gdot1[wid] = s1; }
  }
}

// ---------- GEMM device body: Y = X @ W (K=N=256), optional row renorm, fused sn ----------
template <bool RENORM>
__device__ __forceinline__ void gemm_body(const float* __restrict__ X,
                                          const float* __restrict__ W,
                                          const float* __restrict__ att,
                                          float* __restrict__ Y,
                                          float* __restrict__ sn, int M, int r0) {
  __shared__ float Xs[256][20];
  __shared__ float red[4][16];
  __shared__ float scl[16];
  int tid = threadIdx.x;
  int w = tid >> 6, lane = tid & 63;
  float xv[16];
  #pragma unroll
  for (int i = 0; i < 16; ++i) {
    int r = r0 + i;
    xv[i] = (r < M) ? X[(size_t)r * DD + tid] : 0.f;
  }
  if (RENORM) {
    #pragma unroll
    for (int i = 0; i < 16; ++i) {
      float v = waveSum(xv[i] * xv[i]);
      if (lane == 0) red[w][i] = v;
    }
    __syncthreads();
    if (tid < 16) {
      float t = red[0][tid] + red[1][tid] + red[2][tid] + red[3][tid];
      scl[tid] = fminf(1.f, 1.f / (sqrtf(t) + 1e-12f));
    }
    __syncthreads();
    #pragma unroll
    for (int i = 0; i < 16; ++i) xv[i] *= scl[i];
  }
  #pragma unroll
  for (int i = 0; i < 16; ++i) Xs[tid][i] = xv[i];
  __syncthreads();
  float acc[16];
  #pragma unroll
  for (int i = 0; i < 16; ++i) acc[i] = 0.f;
  const float* wp = W + tid;
  #pragma unroll 8
  for (int k = 0; k < 256; ++k) {
    float wv = wp[(size_t)k * DD];
    const float4* xr = reinterpret_cast<const float4*>(&Xs[k][0]);
    float4 a0 = xr[0], a1 = xr[1], a2 = xr[2], a3 = xr[3];
    acc[0]  += a0.x * wv; acc[1]  += a0.y * wv; acc[2]  += a0.z * wv; acc[3]  += a0.w * wv;
    acc[4]  += a1.x * wv; acc[5]  += a1.y * wv; acc[6]  += a1.z * wv; acc[7]  += a1.w * wv;
    acc[8]  += a2.x * wv; acc[9]  += a2.y * wv; acc[10] += a2.z * wv; acc[11] += a2.w * wv;
    acc[12] += a3.x * wv; acc[13] += a3.y * wv; acc[14] += a3.z * wv; acc[15] += a3.w * wv;
  }
  #pragma unroll
  for (int i = 0; i < 16; ++i) {
    int r = r0 + i;
    if (r < M) Y[(size_t)r * DD + tid] = acc[i];
  }
  float av = att[tid];
  __syncthreads();
  #pragma unroll
  for (int i = 0; i < 16; ++i) {
    float v = waveSum(acc[i] * av);
    if (lane == 0) red[w][i] = v;
  }
  __syncthreads();
  if (tid < 16) {
    int r = r0 + tid;
    if (r < M) sn[r] = red[0][tid] + red[1][tid] + red[2][tid] + red[3][tid];
  }
}

// ---------- K3: gemm0 (blocks 0..158) + fill (blocks 159..1182) ----------
static constexpr int GEMM_BLOCKS = (N_MET + 15) / 16;  // 159
__global__ __launch_bounds__(256) void fill_gemm0_k(
    const int* __restrict__ he_node, const int* __restrict__ he_edge,
    const float* __restrict__ stoich,
    const int* __restrict__ rtg_rxn, const int* __restrict__ rtg_gene,
    int* curE, int2* __restrict__ payE,
    int* curN, int2* __restrict__ payN,
    int* curR, int* __restrict__ geneR,
    int* curG, int* __restrict__ rxnG,
    const float* __restrict__ emb, const float* __restrict__ W0,
    const float* __restrict__ att0, float* __restrict__ xp, float* __restrict__ sn) {
  int blk = blockIdx.x;
  if (blk < GEMM_BLOCKS) {
    gemm_body<true>(emb, W0, att0, xp, sn, N_MET, blk * 16);
  } else {
    int i = (blk - GEMM_BLOCKS) * 256 + threadIdx.x;
    if (i < NE) {
      int n = he_node[i], e = he_edge[i];
      int st = __float_as_int(stoich[i]);
      int pa = atomicAdd(&curE[e], 1); payE[pa] = make_int2(n, st);
      int pb = atomicAdd(&curN[n], 1); payN[pb] = make_int2(e, st);
    }
    if (i < NP) {
      int r = rtg_rxn[i], g = rtg_gene[i];
      int pa = atomicAdd(&curR[r], 1); geneR[pa] = g;
      int pb = atomicAdd(&curG[g], 1); rxnG[pb] = r;
    }
  }
}

// standalone gemm (layer 1)
__global__ __launch_bounds__(256) void gemm1_k(const float* __restrict__ X,
                                               const float* __restrict__ W,
                                               const float* __restrict__ att,
                                               float* __restrict__ Y,
                                               float* __restrict__ sn, int M) {
  gemm_body<false>(X, W, att, Y, sn, M, blockIdx.x * 16);
}

// ---------- 16-deep weighted gather-accumulate over one wave's segment ----------
__device__ __forceinline__ void gatherAcc(float4& acc, const float4* __restrict__ src4,
                                          const int (&rv)[4], const float (&wv)[4],
                                          int nc, int lane) {
  #pragma unroll
  for (int c = 0; c < 4; ++c) {
    int lim = nc - c * 64; if (lim > 64) lim = 64;
    for (int t = 0; t < lim; t += 16) {
      float4 a[16]; float w[16];
      #pragma unroll
      for (int q = 0; q < 16; ++q) {
        int   n = __shfl(rv[c], t + q);
        w[q]    = __shfl(wv[c], t + q);
        a[q]    = src4[(size_t)n * 64 + lane];
      }
      #pragma unroll
      for (int q = 0; q < 16; ++q) {
        acc.x += w[q] * a[q].x; acc.y += w[q] * a[q].y;
        acc.z += w[q] * a[q].z; acc.w += w[q] * a[q].w;
      }
    }
  }
}

// ---------- segment mean (wave per segment), payload stride templated ----------
template <int STRIDE>
__global__ __launch_bounds__(256) void seg_mean_k(const int* __restrict__ offs,
                                                  const int* __restrict__ pay,
                                                  const float* __restrict__ src,
                                                  float* __restrict__ dst, int nseg) {
  int wid = (blockIdx.x * 256 + threadIdx.x) >> 6;
  int lane = threadIdx.x & 63;
  if (wid >= nseg) return;
  int beg = offs[wid], end = offs[wid + 1];
  int cnt = end - beg;
  int nc = cnt < 256 ? cnt : 256;
  int rv[4]; float wv[4];
  #pragma unroll
  for (int c = 0; c < 4; ++c) {
    int j = c * 64 + lane;
    if (j < nc) { rv[c] = pay[(size_t)(beg + j) * STRIDE]; wv[c] = 1.f; }
    else        { rv[c] = 0;                               wv[c] = 0.f; }
  }
  float4 acc = make_float4(0.f, 0.f, 0.f, 0.f);
  gatherAcc(acc, (const float4*)src, rv, wv, nc, lane);
  for (int j = 256; j < cnt; ++j) {   // overflow fallback (cold)
    int n = pay[(size_t)(beg + j) * STRIDE];
    float4 a = ((const float4*)src)[(size_t)n * 64 + lane];
    acc.x += a.x; acc.y += a.y; acc.z += a.z; acc.w += a.w;
  }
  float inv = 1.f / (float)(cnt > 1 ? cnt : 1);
  float4 o; o.x = acc.x * inv; o.y = acc.y * inv; o.z = acc.z * inv; o.w = acc.w * inv;
  ((float4*)dst)[(size_t)wid * 64 + lane] = o;
}

// per-reaction: inline se (scalar segment-mean of gdot) + attention softmax +
// weighted node->edge aggregation. rstat[r] = {se, m, invS, 0}.
__global__ __launch_bounds__(256) void me_k(const int* __restrict__ offs,
                                            const int2* __restrict__ payE,
                                            const float* __restrict__ sn,
                                            const int* __restrict__ offsR,
                                            const int* __restrict__ geneR,
                                            const float* __restrict__ gdot,
                                            const float* __restrict__ xp,
                                            float* __restrict__ me,
                                            float4* __restrict__ rstat) {
  int wid = (blockIdx.x * 256 + threadIdx.x) >> 6;
  int lane = threadIdx.x & 63;
  if (wid >= N_RXN) return;
  // se[wid] = mean over rtg CSR row of gdot[gene]
  int rb = offsR[wid], re = offsR[wid + 1];
  float sacc = 0.f;
  for (int j = rb + lane; j < re; j += 64) sacc += gdot[geneR[j]];
  int rc = re - rb;
  float ser = waveSum(sacc) / (float)(rc > 1 ? rc : 1);

  int beg = offs[wid], end = offs[wid + 1];
  int cnt = end - beg;
  int nc = cnt < 256 ? cnt : 256;
  int nv[4]; float wv[4]; float stv[4];
  float lmax = -1e30f;
  #pragma unroll
  for (int c = 0; c < 4; ++c) {
    int j = c * 64 + lane;
    if (j < nc) {
      int2 p = payE[beg + j];
      float l = sn[p.x] + ser;
      l = (l >= 0.f) ? l : 0.2f * l;
      nv[c] = p.x; wv[c] = l; stv[c] = __int_as_float(p.y);
      lmax = fmaxf(lmax, l);
    } else { nv[c] = 0; wv[c] = -1e30f; stv[c] = 0.f; }
  }
  for (int j = 256 + lane; j < cnt; j += 64) {   // overflow (cold)
    int2 p = payE[beg + j];
    float l = sn[p.x] + ser;
    l = (l >= 0.f) ? l : 0.2f * l;
    lmax = fmaxf(lmax, l);
  }
  float m = waveMax(lmax);
  float s = 0.f;
  #pragma unroll
  for (int c = 0; c < 4; ++c) {
    if (c * 64 + lane < nc) { float e = expf(wv[c] - m); wv[c] = e; s += e; }
    else wv[c] = 0.f;
  }
  for (int j = 256 + lane; j < cnt; j += 64) {   // overflow (cold)
    int2 p = payE[beg + j];
    float l = sn[p.x] + ser;
    l = (l >= 0.f) ? l : 0.2f * l;
    s += expf(l - m);
  }
  s = waveSum(s);
  float invS = 1.f / (s + 1e-16f);
  #pragma unroll
  for (int c = 0; c < 4; ++c) {
    if (c * 64 + lane < nc) wv[c] = stv[c] * wv[c] * invS;
  }
  if (lane == 0) rstat[wid] = make_float4(ser, m, invS, 0.f);
  float4 acc = make_float4(0.f, 0.f, 0.f, 0.f);
  gatherAcc(acc, (const float4*)xp, nv, wv, nc, lane);
  for (int j = 256; j < cnt; ++j) {   // overflow (cold)
    int2 p = payE[beg + j];
    float l = sn[p.x] + ser;
    l = (l >= 0.f) ? l : 0.2f * l;
    float w = __int_as_float(p.y) * expf(l - m) * invS;
    float4 a = ((const float4*)xp)[(size_t)p.x * 64 + lane];
    acc.x += w * a.x; acc.y += w * a.y; acc.z += w * a.z; acc.w += w * a.w;
  }
  float invB = 1.f / (float)(cnt > 1 ? cnt : 1);
  float4 o; o.x = acc.x * invB; o.y = acc.y * invB; o.z = acc.z * invB; o.w = acc.w * invB;
  ((float4*)me)[(size_t)wid * 64 + lane] = o;
}

// per-metabolite: edge->node aggregation + bias + tanh (+ skip + layernorm for layer 1)
template <bool LN>
__global__ __launch_bounds__(256) void out_k(const int* __restrict__ offs,
                                             const int2* __restrict__ payN,
                                             const float* __restrict__ sn,
                                             const float4* __restrict__ rstat,
                                             const float* __restrict__ me,
                                             const float* __restrict__ bias,
                                             const float* __restrict__ ln_g,
                                             const float* __restrict__ ln_b,
                                             float* __restrict__ cur) {
  int wid = (blockIdx.x * 256 + threadIdx.x) >> 6;
  int lane = threadIdx.x & 63;
  if (wid >= N_MET) return;
  int beg = offs[wid], end = offs[wid + 1];
  int cnt = end - beg;
  int nc = cnt < 256 ? cnt : 256;
  float sn_n = sn[wid];
  int rv[4]; float wv[4];
  #pragma unroll
  for (int c = 0; c < 4; ++c) {
    int j = c * 64 + lane;
    if (j < nc) {
      int2 p = payN[beg + j];
      float4 st = rstat[p.x];
      float l = sn_n + st.x;
      l = (l >= 0.f) ? l : 0.2f * l;
      rv[c] = p.x;
      wv[c] = __int_as_float(p.y) * expf(l - st.y) * st.z;
    } else { rv[c] = 0; wv[c] = 0.f; }
  }
  float4 acc = make_float4(0.f, 0.f, 0.f, 0.f);
  gatherAcc(acc, (const float4*)me, rv, wv, nc, lane);
  for (int j = 256; j < cnt; ++j) {   // overflow (cold)
    int2 p = payN[beg + j];
    float4 st = rstat[p.x];
    float l = sn_n + st.x;
    l = (l >= 0.f) ? l : 0.2f * l;
    float w = __int_as_float(p.y) * expf(l - st.y) * st.z;
    float4 a = ((const float4*)me)[(size_t)p.x * 64 + lane];
    acc.x += w * a.x; acc.y += w * a.y; acc.z += w * a.z; acc.w += w * a.w;
  }
  float invD = 1.f / (float)(cnt > 1 ? cnt : 1);
  float4 b4 = ((const float4*)bias)[lane];
  float4 o;
  o.x = tanhf(acc.x * invD + b4.x);
  o.y = tanhf(acc.y * invD + b4.y);
  o.z = tanhf(acc.z * invD + b4.z);
  o.w = tanhf(acc.w * invD + b4.w);
  float4* cur4 = (float4*)cur;
  if (!LN) {
    cur4[(size_t)wid * 64 + lane] = o;
    return;
  }
  float4 p = cur4[(size_t)wid * 64 + lane];
  float4 z; z.x = o.x + p.x; z.y = o.y + p.y; z.z = o.z + p.z; z.w = o.w + p.w;
  float mu = waveSum(z.x + z.y + z.z + z.w) * (1.f / 256.f);
  float4 zc; zc.x = z.x - mu; zc.y = z.y - mu; zc.z = z.z - mu; zc.w = z.w - mu;
  float var = waveSum(zc.x * zc.x + zc.y * zc.y + zc.z * zc.z + zc.w * zc.w) * (1.f / 256.f);
  float rs = 1.f / sqrtf(var + 1e-5f);
  float4 g4 = ((const float4*)ln_g)[lane];
  float4 be4 = ((const float4*)ln_b)[lane];
  float4 r;
  r.x = zc.x * rs * g4.x + be4.x;
  r.y = zc.y * rs * g4.y + be4.y;
  r.z = zc.z * rs * g4.z + be4.z;
  r.w = zc.w * rs * g4.w + be4.w;
  cur4[(size_t)wid * 64 + lane] = r;
}

// ---------- launcher ----------
extern "C" void kernel_launch(void* const* d_in, const int* in_sizes, int n_in,
                              void* d_out, int out_size, void* d_ws, size_t ws_size,
                              hipStream_t stream) {
  const int*   he_node = (const int*)d_in[0];
  const int*   he_edge = (const int*)d_in[1];
  const float* stoich  = (const float*)d_in[2];
  const float* gene_x  = (const float*)d_in[3];
  const int*   rtg_rxn = (const int*)d_in[4];
  const int*   rtg_gene= (const int*)d_in[5];
  const float* emb     = (const float*)d_in[6];
  const float* W0      = (const float*)d_in[7];
  const float* We0     = (const float*)d_in[8];
  const float* att0    = (const float*)d_in[9];
  const float* b0      = (const float*)d_in[10];
  const float* W1      = (const float*)d_in[11];
  const float* We1     = (const float*)d_in[12];
  const float* att1    = (const float*)d_in[13];
  const float* b1      = (const float*)d_in[14];
  const float* ln_g    = (const float*)d_in[15];
  const float* ln_b    = (const float*)d_in[16];
  float* out = (float*)d_out;

  char* base = (char*)d_ws;
  size_t off = 0;
  auto carve = [&](size_t bytes) -> char* {
    char* p = base + off;
    off += (bytes + 255) & ~(size_t)255;
    return p;
  };
  float*  xp    = (float*)carve((size_t)N_MET * DD * 4);
  float*  me    = (float*)carve((size_t)N_RXN * DD * 4);
  float*  cur   = (float*)carve((size_t)N_MET * DD * 4);
  float*  rxnf  = (float*)carve((size_t)N_RXN * DD * 4);
  float*  sn    = (float*)carve((size_t)N_MET * 4);
  float*  ve0   = (float*)carve(DD * 4);
  float*  ve1   = (float*)carve(DD * 4);
  float*  gdot0 = (float*)carve((size_t)N_GENE * 4);
  float*  gdot1 = (float*)carve((size_t)N_GENE * 4);
  float4* rstat = (float4*)carve((size_t)N_RXN * 16);
  int* cnts = (int*)carve((size_t)(N_RXN + N_MET + N_RXN + N_GENE) * 4);
  int* cntE = cnts;
  int* cntN = cntE + N_RXN;
  int* cntR = cntN + N_MET;
  int* cntG = cntR + N_RXN;
  int*  offsE = (int*)carve((N_RXN + 1) * 4);
  int*  curE  = (int*)carve(N_RXN * 4);
  int2* payE  = (int2*)carve((size_t)NE * 8);
  int*  offsN = (int*)carve((N_MET + 1) * 4);
  int*  curN  = (int*)carve(N_MET * 4);
  int2* payN  = (int2*)carve((size_t)NE * 8);
  int*  offsR = (int*)carve((N_RXN + 1) * 4);
  int*  curR  = (int*)carve(N_RXN * 4);
  int*  geneR = (int*)carve((size_t)NP * 4);
  int*  offsG = (int*)carve((N_GENE + 1) * 4);
  int*  curG  = (int*)carve(N_GENE * 4);
  int*  rxnG  = (int*)carve((size_t)NP * 4);

  hipMemsetAsync(cnts, 0, (size_t)(N_RXN + N_MET + N_RXN + N_GENE) * 4, stream);

  // K1: hist + vedot
  hist_vedot_k<<<128 + (NE + 255) / 256, 256, 0, stream>>>(
      he_edge, he_node, rtg_rxn, rtg_gene, cntE, cntN, cntR, cntG,
      We0, att0, We1, att1, ve0, ve1);

  // K2: scan4 + gdot
  int gdot_blocks = (N_GENE + 15) / 16;  // 16 waves per 1024-thread block
  scan_gdot_k<<<4 + gdot_blocks, 1024, 0, stream>>>(
      cntE, N_RXN, offsE, curE,
      cntN, N_MET, offsN, curN,
      cntR, N_RXN, offsR, curR,
      cntG, N_GENE, offsG, curG,
      gene_x, ve0, ve1, gdot0, gdot1);

  // K3: gemm0 (renorm+sn fused) + fill
  fill_gemm0_k<<<GEMM_BLOCKS + (NE + 255) / 256, 256, 0, stream>>>(
      he_node, he_edge, stoich, rtg_rxn, rtg_gene,
      curE, payE, curN, payN, curR, geneR, curG, rxnG,
      emb, W0, att0, xp, sn);

  // layer 0
  me_k<<<(N_RXN + 3) / 4, 256, 0, stream>>>(offsE, payE, sn, offsR, geneR, gdot0,
                                            xp, me, rstat);
  out_k<false><<<(N_MET + 3) / 4, 256, 0, stream>>>(offsN, payN, sn, rstat, me, b0,
                                                    nullptr, nullptr, cur);

  // layer 1
  gemm1_k<<<GEMM_BLOCKS, 256, 0, stream>>>(cur, W1, att1, xp, sn, N_MET);
  me_k<<<(N_RXN + 3) / 4, 256, 0, stream>>>(offsE, payE, sn, offsR, geneR, gdot1,
                                            xp, me, rstat);
  out_k<true><<<(N_MET + 3) / 4, 256, 0, stream>>>(offsN, payN, sn, rstat, me, b1,
                                                   ln_g, ln_b, cur);

  // final readout
  seg_mean_k<2><<<(N_RXN + 3) / 4, 256, 0, stream>>>(offsE, (const int*)payE, cur, rxnf, N_RXN);
  seg_mean_k<1><<<(N_GENE + 3) / 4, 256, 0, stream>>>(offsG, rxnG, rxnf, out, N_GENE);
}

// Round 5
// 228.256 us; speedup vs baseline: 3.3604x; 1.2299x over previous
//
#include <hip/hip_runtime.h>
#include <math.h>

#define DD 256
static constexpr int N_MET  = 2534;
static constexpr int N_RXN  = 4881;
static constexpr int N_GENE = 6607;
static constexpr int NE     = 262144;
static constexpr int NP     = 131072;

static constexpr int NCHUNK = 256;       // NE / 1024
static constexpr int NBE    = 77;        // edge buckets of 64: ceil(4881/64)
static constexpr int NBN    = 80;        // node buckets of 32: ceil(2534/32)
static constexpr int CHS    = 80;        // chunkHist stride
static constexpr int GEMM_BLOCKS = (N_MET + 15) / 16;  // 159

// ---------- wave reductions (64 lanes) ----------
__device__ __forceinline__ float waveSum(float v) {
  #pragma unroll
  for (int o = 32; o > 0; o >>= 1) v += __shfl_xor(v, o, 64);
  return v;
}
__device__ __forceinline__ float waveMax(float v) {
  #pragma unroll
  for (int o = 32; o > 0; o >>= 1) v = fmaxf(v, __shfl_xor(v, o, 64));
  return v;
}
// wave-uniform broadcast via readlane (SGPR result, no ds_bpermute)
__device__ __forceinline__ int   bcasti(int v, int l)   { return __builtin_amdgcn_readlane(v, l); }
__device__ __forceinline__ float bcastf(float v, int l) {
  return __int_as_float(__builtin_amdgcn_readlane(__float_as_int(v), l));
}

// ---------- KH: vedot (blocks 0..31) + hist/chunk-hist (blocks 32..287) ----------
__global__ __launch_bounds__(1024) void KH_k(
    const int* __restrict__ he_node, const int* __restrict__ he_edge,
    const int* __restrict__ rtg_rxn, const int* __restrict__ rtg_gene,
    int* cntE, int* cntN, int* cntR, int* cntG,
    int* __restrict__ chE, int* __restrict__ chN,
    const float* __restrict__ We0, const float* __restrict__ att0,
    const float* __restrict__ We1, const float* __restrict__ att1,
    float* __restrict__ ve0, float* __restrict__ ve1) {
  int blk = blockIdx.x, tid = threadIdx.x;
  if (blk < 32) {
    int wid = blk * 16 + (tid >> 6);   // 0..511
    int lane = tid & 63;
    const float* We = (wid < 256) ? We0 : We1;
    const float* at = (wid < 256) ? att0 : att1;
    int r = wid & 255;
    float4 a = ((const float4*)(We + (size_t)r * DD))[lane];
    float4 v = ((const float4*)(at + DD))[lane];
    float s = waveSum(a.x * v.x + a.y * v.y + a.z * v.z + a.w * v.w);
    if (lane == 0) ((wid < 256) ? ve0 : ve1)[r] = s;
    return;
  }
  int c = blk - 32;                     // chunk id, 0..255
  __shared__ int hE[NBE], hN[NBN];
  if (tid < NBE) hE[tid] = 0;
  if (tid >= 128 && tid < 128 + NBN) hN[tid - 128] = 0;
  __syncthreads();
  int i = c * 1024 + tid;               // i < NE always (256*1024 == NE)
  int n = he_node[i], e = he_edge[i];
  atomicAdd(&cntE[e], 1); atomicAdd(&cntN[n], 1);
  atomicAdd(&hE[e >> 6], 1); atomicAdd(&hN[n >> 5], 1);
  if (i < NP) { atomicAdd(&cntR[rtg_rxn[i]], 1); atomicAdd(&cntG[rtg_gene[i]], 1); }
  __syncthreads();
  if (tid < NBE) chE[c * CHS + tid] = hE[tid];
  if (tid >= 128 && tid < 128 + NBN) chN[c * CHS + (tid - 128)] = hN[tid - 128];
}

// ---------- KScan: scan4 (blk 0-3) + chunkHist column scans (blk 4-13) + gdot ----------
__global__ __launch_bounds__(1024) void KScan_k(
    const int* c0, int n0, int* o0, int* u0,
    const int* c1, int n1, int* o1, int* u1,
    const int* c2, int n2, int* o2, int* u2,
    const int* c3, int n3, int* o3, int* u3,
    int* __restrict__ chE, int* __restrict__ chN,
    const float* __restrict__ gene_x,
    const float* __restrict__ ve0, const float* __restrict__ ve1,
    float* __restrict__ gdot0, float* __restrict__ gdot1) {
  int blk = blockIdx.x, tid = threadIdx.x;
  if (blk < 4) {
    const int* cnt; int n; int* offs; int* cur;
    if      (blk == 0) { cnt = c0; n = n0; offs = o0; cur = u0; }
    else if (blk == 1) { cnt = c1; n = n1; offs = o1; cur = u1; }
    else if (blk == 2) { cnt = c2; n = n2; offs = o2; cur = u2; }
    else               { cnt = c3; n = n3; offs = o3; cur = u3; }
    __shared__ int part[1024];
    int base = tid * 8;
    int v[8]; int s = 0;
    #pragma unroll
    for (int j = 0; j < 8; ++j) { int x = (base + j < n) ? cnt[base + j] : 0; v[j] = x; s += x; }
    part[tid] = s;
    __syncthreads();
    for (int o = 1; o < 1024; o <<= 1) {
      int t = (tid >= o) ? part[tid - o] : 0;
      __syncthreads();
      part[tid] += t;
      __syncthreads();
    }
    int ex = part[tid] - s;
    #pragma unroll
    for (int j = 0; j < 8; ++j) {
      if (base + j < n) { offs[base + j] = ex; cur[base + j] = ex; ex += v[j]; }
    }
    if (tid == 1023) offs[n] = part[1023];
    return;
  }
  if (blk < 14) {
    // column scans: 160 columns (80 E + 80 N), one wave per column
    int colw = (blk - 4) * 16 + (tid >> 6);
    int lane = tid & 63;
    if (colw >= 160) return;
    int side = colw >= 80;
    int b = colw - side * 80;
    int* ch = side ? chN : chE;
    int v[4]; int s = 0;
    int cbase = lane * 4;
    #pragma unroll
    for (int k = 0; k < 4; ++k) { v[k] = ch[(cbase + k) * CHS + b]; s += v[k]; }
    int inc = s;
    #pragma unroll
    for (int o = 1; o < 64; o <<= 1) { int t = __shfl_up(inc, o, 64); if (lane >= o) inc += t; }
    int ex = inc - s;
    #pragma unroll
    for (int k = 0; k < 4; ++k) { int t = v[k]; ch[(cbase + k) * CHS + b] = ex; ex += t; }
    return;
  }
  // gdot: per-gene scalar dots
  int wid = (blk - 14) * 16 + (tid >> 6);
  int lane = tid & 63;
  if (wid >= N_GENE) return;
  float4 a  = ((const float4*)gene_x)[(size_t)wid * 64 + lane];
  float4 v0 = ((const float4*)ve0)[lane];
  float4 v1 = ((const float4*)ve1)[lane];
  float s0 = waveSum(a.x * v0.x + a.y * v0.y + a.z * v0.z + a.w * v0.w);
  float s1 = waveSum(a.x * v1.x + a.y * v1.y + a.z * v1.z + a.w * v1.w);
  if (lane == 0) { gdot0[wid] = s0; gdot1[wid] = s1; }
}

// ---------- KP1: bucket-partition he incidences (blk 0-255) + rtg atomic fill ----------
__global__ __launch_bounds__(1024) void KP1_k(
    const int* __restrict__ he_node, const int* __restrict__ he_edge,
    const float* __restrict__ stoich,
    const int* __restrict__ offsE, const int* __restrict__ offsN,
    const int* __restrict__ chE, const int* __restrict__ chN,
    int4* __restrict__ scrE, int4* __restrict__ scrN,
    const int* __restrict__ rtg_rxn, const int* __restrict__ rtg_gene,
    int* curR, int* __restrict__ geneR,
    int* curG, int* __restrict__ rxnG) {
  int blk = blockIdx.x, tid = threadIdx.x;
  if (blk < NCHUNK) {
    __shared__ int cursE[NBE], cursN[NBN];
    int c = blk;
    if (tid < NBE) cursE[tid] = offsE[64 * tid] + chE[c * CHS + tid];
    if (tid >= 128 && tid < 128 + NBN) {
      int t = tid - 128;
      cursN[t] = offsN[32 * t] + chN[c * CHS + t];
    }
    __syncthreads();
    int i = c * 1024 + tid;
    int n = he_node[i], e = he_edge[i];
    int st = __float_as_int(stoich[i]);
    int dE = atomicAdd(&cursE[e >> 6], 1);
    scrE[dE] = make_int4(e, n, st, 0);
    int dN = atomicAdd(&cursN[n >> 5], 1);
    scrN[dN] = make_int4(n, e, st, 0);
  } else {
    int i = (blk - NCHUNK) * 1024 + tid;   // exactly NP threads (128*1024)
    int r = rtg_rxn[i], g = rtg_gene[i];
    int pa = atomicAdd(&curR[r], 1); geneR[pa] = g;
    int pb = atomicAdd(&curG[g], 1); rxnG[pb] = r;
  }
}

// ---------- GEMM device body: Y = X @ W (K=N=256), optional row renorm, fused sn ----------
template <bool RENORM>
__device__ __forceinline__ void gemm_body(const float* __restrict__ X,
                                          const float* __restrict__ W,
                                          const float* __restrict__ att,
                                          float* __restrict__ Y,
                                          float* __restrict__ sn, int M, int r0) {
  __shared__ float Xs[256][20];
  __shared__ float red[4][16];
  __shared__ float scl[16];
  int tid = threadIdx.x;
  int w = tid >> 6, lane = tid & 63;
  float xv[16];
  #pragma unroll
  for (int i = 0; i < 16; ++i) {
    int r = r0 + i;
    xv[i] = (r < M) ? X[(size_t)r * DD + tid] : 0.f;
  }
  if (RENORM) {
    #pragma unroll
    for (int i = 0; i < 16; ++i) {
      float v = waveSum(xv[i] * xv[i]);
      if (lane == 0) red[w][i] = v;
    }
    __syncthreads();
    if (tid < 16) {
      float t = red[0][tid] + red[1][tid] + red[2][tid] + red[3][tid];
      scl[tid] = fminf(1.f, 1.f / (sqrtf(t) + 1e-12f));
    }
    __syncthreads();
    #pragma unroll
    for (int i = 0; i < 16; ++i) xv[i] *= scl[i];
  }
  #pragma unroll
  for (int i = 0; i < 16; ++i) Xs[tid][i] = xv[i];
  __syncthreads();
  float acc[16];
  #pragma unroll
  for (int i = 0; i < 16; ++i) acc[i] = 0.f;
  const float* wp = W + tid;
  #pragma unroll 8
  for (int k = 0; k < 256; ++k) {
    float wv = wp[(size_t)k * DD];
    const float4* xr = reinterpret_cast<const float4*>(&Xs[k][0]);
    float4 a0 = xr[0], a1 = xr[1], a2 = xr[2], a3 = xr[3];
    acc[0]  += a0.x * wv; acc[1]  += a0.y * wv; acc[2]  += a0.z * wv; acc[3]  += a0.w * wv;
    acc[4]  += a1.x * wv; acc[5]  += a1.y * wv; acc[6]  += a1.z * wv; acc[7]  += a1.w * wv;
    acc[8]  += a2.x * wv; acc[9]  += a2.y * wv; acc[10] += a2.z * wv; acc[11] += a2.w * wv;
    acc[12] += a3.x * wv; acc[13] += a3.y * wv; acc[14] += a3.z * wv; acc[15] += a3.w * wv;
  }
  #pragma unroll
  for (int i = 0; i < 16; ++i) {
    int r = r0 + i;
    if (r < M) Y[(size_t)r * DD + tid] = acc[i];
  }
  float av = att[tid];
  __syncthreads();
  #pragma unroll
  for (int i = 0; i < 16; ++i) {
    float v = waveSum(acc[i] * av);
    if (lane == 0) red[w][i] = v;
  }
  __syncthreads();
  if (tid < 16) {
    int r = r0 + tid;
    if (r < M) sn[r] = red[0][tid] + red[1][tid] + red[2][tid] + red[3][tid];
  }
}

// ---------- KP2: final CSR placement (blk 0..76 edge, 77..156 node) + gemm0 ----------
__global__ __launch_bounds__(256) void KP2_k(
    const int* __restrict__ offsE, const int* __restrict__ offsN,
    const int4* __restrict__ scrE, const int4* __restrict__ scrN,
    int2* __restrict__ payE, int2* __restrict__ payN,
    const float* __restrict__ emb, const float* __restrict__ W0,
    const float* __restrict__ att0, float* __restrict__ xp, float* __restrict__ sn) {
  int blk = blockIdx.x, tid = threadIdx.x;
  if (blk < NBE) {
    __shared__ int curs[64];
    int b = blk;
    int elo = 64 * b;
    int ecnt = min(64, N_RXN - elo);
    if (tid < ecnt) curs[tid] = offsE[elo + tid];
    __syncthreads();
    int lo = offsE[elo], hi = offsE[elo + ecnt];
    for (int j = lo + tid; j < hi; j += 256) {
      int4 r = scrE[j];
      int slot = atomicAdd(&curs[r.x - elo], 1);
      payE[slot] = make_int2(r.y, r.z);
    }
  } else if (blk < NBE + NBN) {
    __shared__ int curs[32];
    int b = blk - NBE;
    int nlo = 32 * b;
    int ncnt = min(32, N_MET - nlo);
    if (tid < ncnt) curs[tid] = offsN[nlo + tid];
    __syncthreads();
    int lo = offsN[nlo], hi = offsN[nlo + ncnt];
    for (int j = lo + tid; j < hi; j += 256) {
      int4 r = scrN[j];
      int slot = atomicAdd(&curs[r.x - nlo], 1);
      payN[slot] = make_int2(r.y, r.z);
    }
  } else {
    gemm_body<true>(emb, W0, att0, xp, sn, N_MET, (blk - NBE - NBN) * 16);
  }
}

// standalone gemm (layer 1)
__global__ __launch_bounds__(256) void gemm1_k(const float* __restrict__ X,
                                               const float* __restrict__ W,
                                               const float* __restrict__ att,
                                               float* __restrict__ Y,
                                               float* __restrict__ sn, int M) {
  gemm_body<false>(X, W, att, Y, sn, M, blockIdx.x * 16);
}

// ---------- 16-deep weighted gather-accumulate (readlane broadcast) ----------
__device__ __forceinline__ void gatherAcc(float4& acc, const float4* __restrict__ src4,
                                          const int (&rv)[4], const float (&wv)[4],
                                          int nc, int lane) {
  #pragma unroll
  for (int c = 0; c < 4; ++c) {
    int lim = nc - c * 64; if (lim > 64) lim = 64;
    for (int t = 0; t < lim; t += 16) {
      float4 a[16]; float w[16];
      #pragma unroll
      for (int q = 0; q < 16; ++q) {
        int   n = bcasti(rv[c], t + q);
        w[q]    = bcastf(wv[c], t + q);
        a[q]    = src4[(size_t)n * 64 + lane];
      }
      #pragma unroll
      for (int q = 0; q < 16; ++q) {
        acc.x += w[q] * a[q].x; acc.y += w[q] * a[q].y;
        acc.z += w[q] * a[q].z; acc.w += w[q] * a[q].w;
      }
    }
  }
}

// ---------- segment mean (wave per segment), payload stride templated ----------
template <int STRIDE>
__global__ __launch_bounds__(256) void seg_mean_k(const int* __restrict__ offs,
                                                  const int* __restrict__ pay,
                                                  const float* __restrict__ src,
                                                  float* __restrict__ dst, int nseg) {
  int wid = (blockIdx.x * 256 + threadIdx.x) >> 6;
  int lane = threadIdx.x & 63;
  if (wid >= nseg) return;
  int beg = offs[wid], end = offs[wid + 1];
  int cnt = end - beg;
  int nc = cnt < 256 ? cnt : 256;
  int rv[4]; float wv[4];
  #pragma unroll
  for (int c = 0; c < 4; ++c) {
    int j = c * 64 + lane;
    if (j < nc) { rv[c] = pay[(size_t)(beg + j) * STRIDE]; wv[c] = 1.f; }
    else        { rv[c] = 0;                               wv[c] = 0.f; }
  }
  float4 acc = make_float4(0.f, 0.f, 0.f, 0.f);
  gatherAcc(acc, (const float4*)src, rv, wv, nc, lane);
  for (int j = 256; j < cnt; ++j) {
    int n = pay[(size_t)(beg + j) * STRIDE];
    float4 a = ((const float4*)src)[(size_t)n * 64 + lane];
    acc.x += a.x; acc.y += a.y; acc.z += a.z; acc.w += a.w;
  }
  float inv = 1.f / (float)(cnt > 1 ? cnt : 1);
  float4 o; o.x = acc.x * inv; o.y = acc.y * inv; o.z = acc.z * inv; o.w = acc.w * inv;
  ((float4*)dst)[(size_t)wid * 64 + lane] = o;
}

// per-reaction: inline se (scalar segment-mean of gdot) + attention softmax +
// weighted node->edge aggregation. rstat[r] = {se, m, invS, 0}.
__global__ __launch_bounds__(256) void me_k(const int* __restrict__ offs,
                                            const int2* __restrict__ payE,
                                            const float* __restrict__ sn,
                                            const int* __restrict__ offsR,
                                            const int* __restrict__ geneR,
                                            const float* __restrict__ gdot,
                                            const float* __restrict__ xp,
                                            float* __restrict__ me,
                                            float4* __restrict__ rstat) {
  int wid = (blockIdx.x * 256 + threadIdx.x) >> 6;
  int lane = threadIdx.x & 63;
  if (wid >= N_RXN) return;
  int rb = offsR[wid], re = offsR[wid + 1];
  float sacc = 0.f;
  for (int j = rb + lane; j < re; j += 64) sacc += gdot[geneR[j]];
  int rc = re - rb;
  float ser = waveSum(sacc) / (float)(rc > 1 ? rc : 1);

  int beg = offs[wid], end = offs[wid + 1];
  int cnt = end - beg;
  int nc = cnt < 256 ? cnt : 256;
  int nv[4]; float wv[4]; float stv[4];
  float lmax = -1e30f;
  #pragma unroll
  for (int c = 0; c < 4; ++c) {
    int j = c * 64 + lane;
    if (j < nc) {
      int2 p = payE[beg + j];
      float l = sn[p.x] + ser;
      l = (l >= 0.f) ? l : 0.2f * l;
      nv[c] = p.x; wv[c] = l; stv[c] = __int_as_float(p.y);
      lmax = fmaxf(lmax, l);
    } else { nv[c] = 0; wv[c] = -1e30f; stv[c] = 0.f; }
  }
  for (int j = 256 + lane; j < cnt; j += 64) {
    int2 p = payE[beg + j];
    float l = sn[p.x] + ser;
    l = (l >= 0.f) ? l : 0.2f * l;
    lmax = fmaxf(lmax, l);
  }
  float m = waveMax(lmax);
  float s = 0.f;
  #pragma unroll
  for (int c = 0; c < 4; ++c) {
    if (c * 64 + lane < nc) { float e = expf(wv[c] - m); wv[c] = e; s += e; }
    else wv[c] = 0.f;
  }
  for (int j = 256 + lane; j < cnt; j += 64) {
    int2 p = payE[beg + j];
    float l = sn[p.x] + ser;
    l = (l >= 0.f) ? l : 0.2f * l;
    s += expf(l - m);
  }
  s = waveSum(s);
  float invS = 1.f / (s + 1e-16f);
  #pragma unroll
  for (int c = 0; c < 4; ++c) {
    if (c * 64 + lane < nc) wv[c] = stv[c] * wv[c] * invS;
  }
  if (lane == 0) rstat[wid] = make_float4(ser, m, invS, 0.f);
  float4 acc = make_float4(0.f, 0.f, 0.f, 0.f);
  gatherAcc(acc, (const float4*)xp, nv, wv, nc, lane);
  for (int j = 256; j < cnt; ++j) {
    int2 p = payE[beg + j];
    float l = sn[p.x] + ser;
    l = (l >= 0.f) ? l : 0.2f * l;
    float w = __int_as_float(p.y) * expf(l - m) * invS;
    float4 a = ((const float4*)xp)[(size_t)p.x * 64 + lane];
    acc.x += w * a.x; acc.y += w * a.y; acc.z += w * a.z; acc.w += w * a.w;
  }
  float invB = 1.f / (float)(cnt > 1 ? cnt : 1);
  float4 o; o.x = acc.x * invB; o.y = acc.y * invB; o.z = acc.z * invB; o.w = acc.w * invB;
  ((float4*)me)[(size_t)wid * 64 + lane] = o;
}

// per-metabolite: edge->node aggregation + bias + tanh (+ skip + layernorm for layer 1)
template <bool LN>
__global__ __launch_bounds__(256) void out_k(const int* __restrict__ offs,
                                             const int2* __restrict__ payN,
                                             const float* __restrict__ sn,
                                             const float4* __restrict__ rstat,
                                             const float* __restrict__ me,
                                             const float* __restrict__ bias,
                                             const float* __restrict__ ln_g,
                                             const float* __restrict__ ln_b,
                                             float* __restrict__ cur) {
  int wid = (blockIdx.x * 256 + threadIdx.x) >> 6;
  int lane = threadIdx.x & 63;
  if (wid >= N_MET) return;
  int beg = offs[wid], end = offs[wid + 1];
  int cnt = end - beg;
  int nc = cnt < 256 ? cnt : 256;
  float sn_n = sn[wid];
  int rv[4]; float wv[4];
  #pragma unroll
  for (int c = 0; c < 4; ++c) {
    int j = c * 64 + lane;
    if (j < nc) {
      int2 p = payN[beg + j];
      float4 st = rstat[p.x];
      float l = sn_n + st.x;
      l = (l >= 0.f) ? l : 0.2f * l;
      rv[c] = p.x;
      wv[c] = __int_as_float(p.y) * expf(l - st.y) * st.z;
    } else { rv[c] = 0; wv[c] = 0.f; }
  }
  float4 acc = make_float4(0.f, 0.f, 0.f, 0.f);
  gatherAcc(acc, (const float4*)me, rv, wv, nc, lane);
  for (int j = 256; j < cnt; ++j) {
    int2 p = payN[beg + j];
    float4 st = rstat[p.x];
    float l = sn_n + st.x;
    l = (l >= 0.f) ? l : 0.2f * l;
    float w = __int_as_float(p.y) * expf(l - st.y) * st.z;
    float4 a = ((const float4*)me)[(size_t)p.x * 64 + lane];
    acc.x += w * a.x; acc.y += w * a.y; acc.z += w * a.z; acc.w += w * a.w;
  }
  float invD = 1.f / (float)(cnt > 1 ? cnt : 1);
  float4 b4 = ((const float4*)bias)[lane];
  float4 o;
  o.x = tanhf(acc.x * invD + b4.x);
  o.y = tanhf(acc.y * invD + b4.y);
  o.z = tanhf(acc.z * invD + b4.z);
  o.w = tanhf(acc.w * invD + b4.w);
  float4* cur4 = (float4*)cur;
  if (!LN) {
    cur4[(size_t)wid * 64 + lane] = o;
    return;
  }
  float4 p = cur4[(size_t)wid * 64 + lane];
  float4 z; z.x = o.x + p.x; z.y = o.y + p.y; z.z = o.z + p.z; z.w = o.w + p.w;
  float mu = waveSum(z.x + z.y + z.z + z.w) * (1.f / 256.f);
  float4 zc; zc.x = z.x - mu; zc.y = z.y - mu; zc.z = z.z - mu; zc.w = z.w - mu;
  float var = waveSum(zc.x * zc.x + zc.y * zc.y + zc.z * zc.z + zc.w * zc.w) * (1.f / 256.f);
  float rs = 1.f / sqrtf(var + 1e-5f);
  float4 g4 = ((const float4*)ln_g)[lane];
  float4 be4 = ((const float4*)ln_b)[lane];
  float4 r;
  r.x = zc.x * rs * g4.x + be4.x;
  r.y = zc.y * rs * g4.y + be4.y;
  r.z = zc.z * rs * g4.z + be4.z;
  r.w = zc.w * rs * g4.w + be4.w;
  cur4[(size_t)wid * 64 + lane] = r;
}

// ---------- launcher ----------
extern "C" void kernel_launch(void* const* d_in, const int* in_sizes, int n_in,
                              void* d_out, int out_size, void* d_ws, size_t ws_size,
                              hipStream_t stream) {
  const int*   he_node = (const int*)d_in[0];
  const int*   he_edge = (const int*)d_in[1];
  const float* stoich  = (const float*)d_in[2];
  const float* gene_x  = (const float*)d_in[3];
  const int*   rtg_rxn = (const int*)d_in[4];
  const int*   rtg_gene= (const int*)d_in[5];
  const float* emb     = (const float*)d_in[6];
  const float* W0      = (const float*)d_in[7];
  const float* We0     = (const float*)d_in[8];
  const float* att0    = (const float*)d_in[9];
  const float* b0      = (const float*)d_in[10];
  const float* W1      = (const float*)d_in[11];
  const float* We1     = (const float*)d_in[12];
  const float* att1    = (const float*)d_in[13];
  const float* b1      = (const float*)d_in[14];
  const float* ln_g    = (const float*)d_in[15];
  const float* ln_b    = (const float*)d_in[16];
  float* out = (float*)d_out;

  char* base = (char*)d_ws;
  size_t off = 0;
  auto carve = [&](size_t bytes) -> char* {
    char* p = base + off;
    off += (bytes + 255) & ~(size_t)255;
    return p;
  };
  float*  xp    = (float*)carve((size_t)N_MET * DD * 4);
  float*  me    = (float*)carve((size_t)N_RXN * DD * 4);
  float*  cur   = (float*)carve((size_t)N_MET * DD * 4);
  float*  rxnf  = (float*)carve((size_t)N_RXN * DD * 4);
  float*  sn    = (float*)carve((size_t)N_MET * 4);
  float*  ve0   = (float*)carve(DD * 4);
  float*  ve1   = (float*)carve(DD * 4);
  float*  gdot0 = (float*)carve((size_t)N_GENE * 4);
  float*  gdot1 = (float*)carve((size_t)N_GENE * 4);
  float4* rstat = (float4*)carve((size_t)N_RXN * 16);
  int* cnts = (int*)carve((size_t)(N_RXN + N_MET + N_RXN + N_GENE) * 4);
  int* cntE = cnts;
  int* cntN = cntE + N_RXN;
  int* cntR = cntN + N_MET;
  int* cntG = cntR + N_RXN;
  int*  offsE = (int*)carve((N_RXN + 1) * 4);
  int*  curE  = (int*)carve(N_RXN * 4);
  int2* payE  = (int2*)carve((size_t)NE * 8);
  int*  offsN = (int*)carve((N_MET + 1) * 4);
  int*  curN  = (int*)carve(N_MET * 4);
  int2* payN  = (int2*)carve((size_t)NE * 8);
  int*  offsR = (int*)carve((N_RXN + 1) * 4);
  int*  curR  = (int*)carve(N_RXN * 4);
  int*  geneR = (int*)carve((size_t)NP * 4);
  int*  offsG = (int*)carve((N_GENE + 1) * 4);
  int*  curG  = (int*)carve(N_GENE * 4);
  int*  rxnG  = (int*)carve((size_t)NP * 4);
  int4* scrE  = (int4*)carve((size_t)NE * 16);
  int4* scrN  = (int4*)carve((size_t)NE * 16);
  int*  chE   = (int*)carve((size_t)NCHUNK * CHS * 4);
  int*  chN   = (int*)carve((size_t)NCHUNK * CHS * 4);

  hipMemsetAsync(cnts, 0, (size_t)(N_RXN + N_MET + N_RXN + N_GENE) * 4, stream);

  // KH: vedot + histograms (global counters + per-chunk bucket hists)
  KH_k<<<32 + NCHUNK, 1024, 0, stream>>>(
      he_node, he_edge, rtg_rxn, rtg_gene, cntE, cntN, cntR, cntG,
      chE, chN, We0, att0, We1, att1, ve0, ve1);

  // KScan: scan4 + chunkHist column scans + gdot
  int gdot_blocks = (N_GENE + 15) / 16;
  KScan_k<<<14 + gdot_blocks, 1024, 0, stream>>>(
      cntE, N_RXN, offsE, curE,
      cntN, N_MET, offsN, curN,
      cntR, N_RXN, offsR, curR,
      cntG, N_GENE, offsG, curG,
      chE, chN, gene_x, ve0, ve1, gdot0, gdot1);

  // KP1: bucket partition (LDS cursors, no global atomics) + rtg atomic fill
  KP1_k<<<NCHUNK + NP / 1024, 1024, 0, stream>>>(
      he_node, he_edge, stoich, offsE, offsN, chE, chN, scrE, scrN,
      rtg_rxn, rtg_gene, curR, geneR, curG, rxnG);

  // KP2: final CSR placement (locality-bounded scatter) + gemm0
  KP2_k<<<NBE + NBN + GEMM_BLOCKS, 256, 0, stream>>>(
      offsE, offsN, scrE, scrN, payE, payN, emb, W0, att0, xp, sn);

  // layer 0
  me_k<<<(N_RXN + 3) / 4, 256, 0, stream>>>(offsE, payE, sn, offsR, geneR, gdot0,
                                            xp, me, rstat);
  out_k<false><<<(N_MET + 3) / 4, 256, 0, stream>>>(offsN, payN, sn, rstat, me, b0,
                                                    nullptr, nullptr, cur);

  // layer 1
  gemm1_k<<<GEMM_BLOCKS, 256, 0, stream>>>(cur, W1, att1, xp, sn, N_MET);
  me_k<<<(N_RXN + 3) / 4, 256, 0, stream>>>(offsE, payE, sn, offsR, geneR, gdot1,
                                            xp, me, rstat);
  out_k<true><<<(N_MET + 3) / 4, 256, 0, stream>>>(offsN, payN, sn, rstat, me, b1,
                                                   ln_g, ln_b, cur);

  // final readout
  seg_mean_k<2><<<(N_RXN + 3) / 4, 256, 0, stream>>>(offsE, (const int*)payE, cur, rxnf, N_RXN);
  seg_mean_k<1><<<(N_GENE + 3) / 4, 256, 0, stream>>>(offsG, rxnG, rxnf, out, N_GENE);
}